// Round 8
// baseline (17497.275 us; speedup 1.0000x reference)
//
#include <hip/hip_runtime.h>
#include <math.h>

#define KD 256
#define UD 64
#define XD 128

// ws float offsets (single-step machinery, unchanged from R6)
#define OFF_V     0
#define OFF_WA    65536
#define OFF_H     131072
#define OFF_G     196608
#define OFF_K0    212992
#define OFF_MI    229376
#define OFF_MP    233472
#define OFF_v     266240
#define OFF_ATV   266496
#define OFF_Z     266752
#define OFF_QG    266816
#define OFF_QD    267072
#define OFF_RD    267328
#define OFF_KV    267392
#define OFF_CV    267456
#define OFF_NKT   267520
// SDA fp64 buffers start at float index 278528 (= double index 139264)
#define DBASE     139264
#define DBUF      65536

__device__ __forceinline__ void inv4(float* D) {
#pragma unroll
  for (int p = 0; p < 4; ++p) {
    float ip = 1.0f / D[p * 4 + p];
#pragma unroll
    for (int i2 = 0; i2 < 4; ++i2)
      if (i2 != p) {
        float f = D[i2 * 4 + p] * ip;
#pragma unroll
        for (int j = 0; j < 4; ++j)
          if (j != p) D[i2 * 4 + j] -= f * D[p * 4 + j];
        D[i2 * 4 + p] = -f;
      }
#pragma unroll
    for (int j = 0; j < 4; ++j)
      if (j != p) D[p * 4 + j] *= ip;
    D[p * 4 + p] = ip;
  }
}

#define R16(OP) OP(0) OP(1) OP(2) OP(3) OP(4) OP(5) OP(6) OP(7) OP(8) OP(9) OP(10) OP(11) OP(12) OP(13) OP(14) OP(15)

// ================= init =================
__global__ __launch_bounds__(256) void k_init(
    const float* __restrict__ W, const float* __restrict__ bphi,
    const float* __restrict__ xg, const float* __restrict__ qlog,
    const float* __restrict__ rlog, float* __restrict__ ws)
{
  const int w = blockIdx.x, t = threadIdx.x;
  if (w < 4 && t < 64) {
    int i = w * 64 + t;
    float acc = 0.f;
    for (int p = 0; p < XD; ++p) acc = fmaf(W[i * XD + p], xg[p], acc);
    float g = acc + bphi[i];
    float qd = expf(qlog[i]);
    ws[OFF_QD + i] = qd; ws[OFF_QG + i] = qd * g; ws[OFF_v + i] = qd * g;
  }
  if (w == 4 && t < UD) ws[OFF_RD + t] = expf(rlog[t]);
}

// ================= cvt: fp64 seeds (E1=A, H1=Q, e1=0, h1=-Qg, B64, Bs64) =================
__global__ __launch_bounds__(256) void k_cvt(
    const float* __restrict__ A, const float* __restrict__ B, float* __restrict__ ws)
{
  double* base = (double*)ws + DBASE;
  double* E1 = base + 0 * DBUF;
  double* H1 = base + 2 * DBUF;
  double* MB = base + 14 * DBUF;
  double* B64 = MB;
  double* Bs64 = MB + 16384;
  double* eA = MB + 32768;
  double* hA = MB + 33024;
  int id = blockIdx.x * 256 + threadIdx.x;   // 0..65535
  E1[id] = (double)A[id];
  int i = id >> 8, j = id & 255;
  H1[id] = (i == j) ? (double)ws[OFF_QD + i] : 0.0;
  if (id < 16384) {
    int m = id & 63;
    B64[id] = (double)B[id];
    Bs64[id] = (double)B[id] / (double)ws[OFF_RD + m];
  }
  if (id < 256) {
    eA[id] = 0.0;
    hA[id] = -(double)ws[OFF_QG + id];
  }
}

// ================= fp64 batched GEMM/matvec job kernel =================
struct GJ { const double* A; const double* B; const double* C; double* O;
            int sA0, sA1, sB0, sB1, K, addI; };
struct VJ { const double* M1; const double* x; const double* a; double* o;
            int s0, s1; double sgn; };

__global__ __launch_bounds__(256) void k_gemm64(GJ g0, GJ g1, GJ g2, int ng,
                                                VJ v0, VJ v1, VJ v2)
{
  __shared__ double As[32 * 33];
  __shared__ double Bs[32 * 33];
  __shared__ double xs[256];
  const int wg = blockIdx.x, t = threadIdx.x;
  if (wg < ng * 64) {
    GJ j = (wg < 64) ? g0 : (wg < 128) ? g1 : g2;
    const int w2 = wg & 63;
    const int tm0 = (w2 >> 3) * 32, tn0 = (w2 & 7) * 32;
    const int rq = t >> 5, c = t & 31;
    double a0 = 0, a1 = 0, a2 = 0, a3 = 0;
    for (int k0 = 0; k0 < j.K; k0 += 32) {
#pragma unroll
      for (int q = 0; q < 4; ++q) {
        int lin = q * 256 + t; int r = lin >> 5, kk = lin & 31;
        As[r * 33 + kk] = j.A[(long)(tm0 + r) * j.sA0 + (long)(k0 + kk) * j.sA1];
        Bs[r * 33 + kk] = j.B[(long)(k0 + r) * j.sB0 + (long)(tn0 + kk) * j.sB1];
      }
      __syncthreads();
#pragma unroll 8
      for (int kk = 0; kk < 32; ++kk) {
        double b = Bs[kk * 33 + c];
        a0 = fma(As[(rq * 4 + 0) * 33 + kk], b, a0);
        a1 = fma(As[(rq * 4 + 1) * 33 + kk], b, a1);
        a2 = fma(As[(rq * 4 + 2) * 33 + kk], b, a2);
        a3 = fma(As[(rq * 4 + 3) * 33 + kk], b, a3);
      }
      __syncthreads();
    }
    const int n = tn0 + c;
    double av[4] = {a0, a1, a2, a3};
#pragma unroll
    for (int i2 = 0; i2 < 4; ++i2) {
      int m = tm0 + rq * 4 + i2;
      double v = av[i2];
      if (j.C) v += j.C[m * 256 + n];
      if (j.addI && m == n) v += 1.0;
      j.O[m * 256 + n] = v;
    }
  } else {
    const int vi = wg - ng * 64;
    VJ j = (vi == 0) ? v0 : (vi == 1) ? v1 : v2;
    xs[t] = j.x[t];
    __syncthreads();
    double acc = 0;
#pragma unroll 8
    for (int k2 = 0; k2 < 256; ++k2)
      acc = fma(j.M1[(long)t * j.s0 + (long)k2 * j.s1], xs[k2], acc);
    double o = j.sgn * acc;
    if (j.a) o += j.a[t];
    j.o[t] = o;
  }
}

// ================= fp64 256x256 in-place GJ inverse (one WG, blocked-32) =================
// R8 rewrite: thread = (column c = t&255, row-quarter qr = t>>8). Pivot factors
// f[r][q] are wave-uniform LDS broadcasts (no register arrays -> no spill at the
// 1024-thread 64-VGPR cap, which made R7's version 1.7 ms of scratch stalls).
__global__ __launch_bounds__(1024) void k_inv64(double* __restrict__ Y)
{
  __shared__ double Pc[256 * 33];   // panel columns (f block): Pc[r][q] = Y[r][pc0+q]
  __shared__ double Rw[32 * 258];   // panel rows; after U-step: U = Dinv @ rows
  __shared__ double Dv[32 * 33];    // D -> Dinv
  const int tt = threadIdx.x;
  const int c  = tt & 255;          // owned column
  const int qr = tt >> 8;           // row quarter (0..3)
  for (int k = 0; k < 8; ++k) {
    const int pc0 = k * 32;
    // stage panel columns + panel rows (8192 elems each / 1024 threads)
#pragma unroll
    for (int q = 0; q < 8; ++q) {
      int lin = q * 1024 + tt;
      int r = lin >> 5, cc = lin & 31;
      Pc[r * 33 + cc] = Y[r * 256 + pc0 + cc];
      int rr2 = lin >> 8, c2 = lin & 255;
      Rw[rr2 * 258 + c2] = Y[(pc0 + rr2) * 256 + c2];
    }
    __syncthreads();
    if (tt < 32) {
#pragma unroll 8
      for (int m = 0; m < 32; ++m) Dv[tt * 33 + m] = Rw[tt * 258 + pc0 + m];
    }
    __syncthreads();
    // serial 32x32 in-place GJ inverse of Dv (lanes 0..31, lockstep)
    if (tt < 32) {
      const int r = tt;
      for (int p = 0; p < 32; ++p) {
        double ipiv = 1.0 / Dv[p * 33 + p];
        double f = Dv[r * 33 + p];
        double gml = f * ipiv;
        bool ip = (r == p);
#pragma unroll 8
        for (int j = 0; j < 32; ++j) {
          double prj = Dv[p * 33 + j];
          double nv = ip ? prj * ipiv : Dv[r * 33 + j] - gml * prj;
          if (j == p) nv = ip ? ipiv : -gml;
          Dv[r * 33 + j] = nv;
        }
      }
    }
    __syncthreads();
    // U = Dinv @ Rw : thread computes U rows qr*8..qr*8+7 for its column c
    {
      double un[8];
#pragma unroll
      for (int i = 0; i < 8; ++i) {
        int q = qr * 8 + i;
        double acc = 0.0;
#pragma unroll 8
        for (int m = 0; m < 32; ++m) acc = fma(Dv[q * 33 + m], Rw[m * 258 + c], acc);
        un[i] = acc;
      }
      __syncthreads();
#pragma unroll
      for (int i = 0; i < 8; ++i) Rw[(qr * 8 + i) * 258 + c] = un[i];
    }
    __syncthreads();
    // global update: thread owns column c, rows qr*64..qr*64+63
    const bool cpan = (c >= pc0 && c < pc0 + 32);
    const int cq = c - pc0;
    for (int i = 0; i < 64; ++i) {
      const int r = qr * 64 + i;
      const bool rpan = (r >= pc0 && r < pc0 + 32);
      double outv;
      if (rpan) {
        int pr = r - pc0;
        outv = cpan ? Dv[pr * 33 + cq] : Rw[pr * 258 + c];
      } else if (cpan) {
        double acc = 0.0;
#pragma unroll 8
        for (int m = 0; m < 32; ++m) acc = fma(Pc[r * 33 + m], Dv[m * 33 + cq], acc);
        outv = -acc;
      } else {
        double acc = Y[r * 256 + c];
#pragma unroll 8
        for (int q = 0; q < 32; ++q) acc = fma(-Pc[r * 33 + q], Rw[q * 258 + c], acc);
        outv = acc;
      }
      Y[r * 256 + c] = outv;
    }
    __syncthreads();
  }
}

// ================= fin2: V = (float)H_final, vv = -(float)h_final =================
__global__ __launch_bounds__(256) void k_fin2(float* __restrict__ ws)
{
  double* base = (double*)ws + DBASE;
  double* Hf = base + 8 * DBUF;              // SetC.H
  double* hf = base + 14 * DBUF + 34048;     // hC
  int id = blockIdx.x * 256 + threadIdx.x;
  ws[OFF_V + id] = (float)Hf[id];
  if (id < 256) ws[OFF_v + id] = -(float)hf[id];
}

// ================= single Riccati step (verified R6 kernels, unchanged) =================
__global__ __launch_bounds__(256) void k_ph1(
    const float* __restrict__ A, const float* __restrict__ B,
    float* __restrict__ ws)
{
  const int u = blockIdx.x, t = threadIdx.x;
  const int sb = u & 7, hb = u >> 3;
  const int rb = sb * 32, cb0 = hb * 32, m0 = hb * 8;
  float* V   = ws + OFF_V;
  float* WAg = ws + OFF_WA;

  __shared__ float sVt[256 * 36];
  __shared__ float sA [256 * 36];
  __shared__ float sBsl[256 * 8];
  __shared__ float sBr[32 * 64];
  __shared__ float svv[256];
  __shared__ float sVB[32 * 9];
  __shared__ float sRed[8 * 36];

  for (int q = 0; q < 8; ++q) {
    int idx = q * 256 + t; int p = idx >> 3, r4 = (idx & 7) * 4;
    *(float4*)&sVt[p * 36 + r4] = *(const float4*)(V + p * KD + rb + r4);
  }
  for (int q = 0; q < 8; ++q) {
    int idx = q * 256 + t; int p = idx >> 3, r4 = (idx & 7) * 4;
    *(float4*)&sA[p * 36 + r4] = *(const float4*)(A + p * KD + cb0 + r4);
  }
  for (int q = 0; q < 2; ++q) {
    int idx = q * 256 + t; int p = idx >> 1, j4 = (idx & 1) * 4;
    *(float4*)&sBsl[p * 8 + j4] = *(const float4*)(B + p * UD + m0 + j4);
  }
  for (int q = 0; q < 2; ++q) {
    int idx = q * 256 + t; int r = idx >> 4, a4 = (idx & 15) * 4;
    *(float4*)&sBr[r * 64 + a4] = *(const float4*)(B + (rb + r) * UD + a4);
  }
  svv[t] = ws[OFF_v + t];
  __syncthreads();

  const int j = t & 31, rq = t >> 5;
  float4 acc = {0.f, 0.f, 0.f, 0.f};
  float avb0 = 0.f, avb1 = 0.f, avb2 = 0.f, avb3 = 0.f;
  const bool dovb = (j < 8);
#pragma unroll 8
  for (int p = 0; p < KD; ++p) {
    float4 v4 = *(const float4*)&sVt[p * 36 + rq * 4];
    float a = sA[p * 36 + j];
    acc.x = fmaf(v4.x, a, acc.x);
    acc.y = fmaf(v4.y, a, acc.y);
    acc.z = fmaf(v4.z, a, acc.z);
    acc.w = fmaf(v4.w, a, acc.w);
    if (dovb) {
      float b = sBsl[p * 8 + j];
      avb0 = fmaf(v4.x, b, avb0);
      avb1 = fmaf(v4.y, b, avb1);
      avb2 = fmaf(v4.z, b, avb2);
      avb3 = fmaf(v4.w, b, avb3);
    }
  }
  WAg[(rb + 4 * rq + 0) * KD + cb0 + j] = acc.x;
  WAg[(rb + 4 * rq + 1) * KD + cb0 + j] = acc.y;
  WAg[(rb + 4 * rq + 2) * KD + cb0 + j] = acc.z;
  WAg[(rb + 4 * rq + 3) * KD + cb0 + j] = acc.w;
  if (dovb) {
    sVB[(4 * rq + 0) * 9 + j] = avb0;
    sVB[(4 * rq + 1) * 9 + j] = avb1;
    sVB[(4 * rq + 2) * 9 + j] = avb2;
    sVB[(4 * rq + 3) * 9 + j] = avb3;
  }
  if (sb == 0) {
    int c = t & 31, part = t >> 5;
    float acc2 = 0.f;
#pragma unroll 8
    for (int p = part * 32; p < part * 32 + 32; ++p) acc2 = fmaf(sA[p * 36 + c], svv[p], acc2);
    sRed[part * 36 + c] = acc2;
  }
  if (sb == 1 && t < 64) {
    int jz = t & 7, part = t >> 3;
    float acc2 = 0.f;
#pragma unroll 8
    for (int p = part * 32; p < part * 32 + 32; ++p) acc2 = fmaf(sBsl[p * 8 + jz], svv[p], acc2);
    sRed[part * 36 + jz] = acc2;
  }
  __syncthreads();
  {
    int a = t & 63, j2 = (t >> 6) * 2;
    float mp0 = 0.f, mp1 = 0.f;
#pragma unroll 8
    for (int r = 0; r < 32; ++r) {
      float bv = sBr[r * 64 + a];
      mp0 = fmaf(bv, sVB[r * 9 + j2 + 0], mp0);
      mp1 = fmaf(bv, sVB[r * 9 + j2 + 1], mp1);
    }
    ws[OFF_MP + sb * 4096 + a * 64 + m0 + j2 + 0] = mp0;
    ws[OFF_MP + sb * 4096 + a * 64 + m0 + j2 + 1] = mp1;
  }
  if (sb == 0 && t < 32) {
    float a2 = 0.f;
#pragma unroll
    for (int pt = 0; pt < 8; ++pt) a2 += sRed[pt * 36 + t];
    ws[OFF_ATV + cb0 + t] = a2;
  }
  if (sb == 1 && t < 8) {
    float a2 = 0.f;
#pragma unroll
    for (int pt = 0; pt < 8; ++pt) a2 += sRed[pt * 36 + t];
    ws[OFF_Z + m0 + t] = a2;
  }
}

__global__ __launch_bounds__(256) void k_ph2(
    const float* __restrict__ A, const float* __restrict__ B,
    float* __restrict__ ws, int last)
{
  const int w = blockIdx.x, t = threadIdx.x;
  const int u = w - 1;
  float* WAg = ws + OFF_WA;
  float* MI  = ws + OFF_MI;

  __shared__ float sWA[256 * 33];
  __shared__ float sA [256 * 36];
  __shared__ float sBsl[256 * 8];
  __shared__ float scr[608];
  __shared__ float wred[256];

  if (w == 0) {
    float* sPR = scr;
    float* sF  = scr + 280;
    const int i = t & 63, cg = t >> 6;
    const float rdi = ws[OFF_RD + i];
    float rr[16];
    {
      float4 s0 = {0,0,0,0}, s1 = {0,0,0,0}, s2 = {0,0,0,0}, s3 = {0,0,0,0};
#pragma unroll
      for (int sb2 = 0; sb2 < 8; ++sb2) {
        const float* mp = ws + OFF_MP + sb2 * 4096 + i * 64 + cg * 16;
        float4 a0 = *(const float4*)(mp + 0);
        float4 a1 = *(const float4*)(mp + 4);
        float4 a2 = *(const float4*)(mp + 8);
        float4 a3 = *(const float4*)(mp + 12);
        s0.x += a0.x; s0.y += a0.y; s0.z += a0.z; s0.w += a0.w;
        s1.x += a1.x; s1.y += a1.y; s1.z += a1.z; s1.w += a1.w;
        s2.x += a2.x; s2.y += a2.y; s2.z += a2.z; s2.w += a2.w;
        s3.x += a3.x; s3.y += a3.y; s3.z += a3.z; s3.w += a3.w;
      }
      rr[0]=s0.x; rr[1]=s0.y; rr[2]=s0.z; rr[3]=s0.w;
      rr[4]=s1.x; rr[5]=s1.y; rr[6]=s1.z; rr[7]=s1.w;
      rr[8]=s2.x; rr[9]=s2.y; rr[10]=s2.z; rr[11]=s2.w;
      rr[12]=s3.x; rr[13]=s3.y; rr[14]=s3.z; rr[15]=s3.w;
#define DIAG(j) rr[j] += (cg * 16 + j == i) ? rdi : 0.f;
      R16(DIAG)
#undef DIAG
    }
    for (int k = 0; k < 16; ++k) {
      const int prw = i - 4 * k;
      const bool inblk = (unsigned)prw < 4u;
      if (inblk) {
#define ST(j) sPR[prw * 68 + cg * 16 + j] = rr[j];
        R16(ST)
#undef ST
      }
      if (cg == (k >> 2)) {
        switch (k & 3) {
          case 0: sF[i*5+0]=rr[0];  sF[i*5+1]=rr[1];  sF[i*5+2]=rr[2];  sF[i*5+3]=rr[3];  break;
          case 1: sF[i*5+0]=rr[4];  sF[i*5+1]=rr[5];  sF[i*5+2]=rr[6];  sF[i*5+3]=rr[7];  break;
          case 2: sF[i*5+0]=rr[8];  sF[i*5+1]=rr[9];  sF[i*5+2]=rr[10]; sF[i*5+3]=rr[11]; break;
          default:sF[i*5+0]=rr[12]; sF[i*5+1]=rr[13]; sF[i*5+2]=rr[14]; sF[i*5+3]=rr[15]; break;
        }
      }
      __syncthreads();
      float D[16];
#pragma unroll
      for (int q = 0; q < 4; ++q) {
        D[q*4+0] = sPR[q*68 + 4*k + 0];
        D[q*4+1] = sPR[q*68 + 4*k + 1];
        D[q*4+2] = sPR[q*68 + 4*k + 2];
        D[q*4+3] = sPR[q*68 + 4*k + 3];
      }
      inv4(D);
      float f0 = sF[i*5+0], f1 = sF[i*5+1], f2 = sF[i*5+2], f3 = sF[i*5+3];
      float g0, g1, g2, g3;
      if (inblk) {
        g0 = prw==0?D[0]:prw==1?D[4]:prw==2?D[8]:D[12];
        g1 = prw==0?D[1]:prw==1?D[5]:prw==2?D[9]:D[13];
        g2 = prw==0?D[2]:prw==1?D[6]:prw==2?D[10]:D[14];
        g3 = prw==0?D[3]:prw==1?D[7]:prw==2?D[11]:D[15];
      } else {
        g0 = f0*D[0] + f1*D[4] + f2*D[8]  + f3*D[12];
        g1 = f0*D[1] + f1*D[5] + f2*D[9]  + f3*D[13];
        g2 = f0*D[2] + f1*D[6] + f2*D[10] + f3*D[14];
        g3 = f0*D[3] + f1*D[7] + f2*D[11] + f3*D[15];
      }
#define CHUNK(c4)                                                         \
      {                                                                   \
        float4 p0 = *(const float4*)&sPR[0 * 68 + cg * 16 + (c4) * 4];    \
        float4 p1 = *(const float4*)&sPR[1 * 68 + cg * 16 + (c4) * 4];    \
        float4 p2 = *(const float4*)&sPR[2 * 68 + cg * 16 + (c4) * 4];    \
        float4 p3 = *(const float4*)&sPR[3 * 68 + cg * 16 + (c4) * 4];    \
        float n0 = fmaf(g0,p0.x, fmaf(g1,p1.x, fmaf(g2,p2.x, g3*p3.x)));  \
        float n1 = fmaf(g0,p0.y, fmaf(g1,p1.y, fmaf(g2,p2.y, g3*p3.y)));  \
        float n2 = fmaf(g0,p0.z, fmaf(g1,p1.z, fmaf(g2,p2.z, g3*p3.z)));  \
        float n3 = fmaf(g0,p0.w, fmaf(g1,p1.w, fmaf(g2,p2.w, g3*p3.w)));  \
        if (inblk) { rr[(c4)*4+0]=n0; rr[(c4)*4+1]=n1; rr[(c4)*4+2]=n2; rr[(c4)*4+3]=n3; } \
        else { rr[(c4)*4+0]-=n0; rr[(c4)*4+1]-=n1; rr[(c4)*4+2]-=n2; rr[(c4)*4+3]-=n3; }   \
      }
      CHUNK(0) CHUNK(1) CHUNK(2) CHUNK(3)
#undef CHUNK
      if (cg == (k >> 2)) {
        switch (k & 3) {
          case 0: rr[0] = inblk? g0:-g0; rr[1] = inblk? g1:-g1; rr[2] = inblk? g2:-g2; rr[3] = inblk? g3:-g3; break;
          case 1: rr[4] = inblk? g0:-g0; rr[5] = inblk? g1:-g1; rr[6] = inblk? g2:-g2; rr[7] = inblk? g3:-g3; break;
          case 2: rr[8] = inblk? g0:-g0; rr[9] = inblk? g1:-g1; rr[10]= inblk? g2:-g2; rr[11]= inblk? g3:-g3; break;
          default:rr[12]= inblk? g0:-g0; rr[13]= inblk? g1:-g1; rr[14]= inblk? g2:-g2; rr[15]= inblk? g3:-g3; break;
        }
      }
      __syncthreads();
    }
    *(float4*)(MI + i * 64 + cg * 16 + 0)  = *(float4*)&rr[0];
    *(float4*)(MI + i * 64 + cg * 16 + 4)  = *(float4*)&rr[4];
    *(float4*)(MI + i * 64 + cg * 16 + 8)  = *(float4*)&rr[8];
    *(float4*)(MI + i * 64 + cg * 16 + 12) = *(float4*)&rr[12];
    if (last) {
      float p2 = 0.f;
#define KV(j) p2 = fmaf(rr[j], ws[OFF_Z + cg * 16 + j], p2);
      R16(KV)
#undef KV
      wred[i * 4 + cg] = p2;
      __syncthreads();
      if (t < 64) ws[OFF_KV + t] = wred[t*4+0] + wred[t*4+1] + wred[t*4+2] + wred[t*4+3];
    }
  } else {
    const int sb = u & 7, hb = u >> 3;
    const int rb = sb * 32, cb0 = hb * 32, m0 = hb * 8;
    for (int q = 0; q < 8; ++q) {
      int idx = q * 256 + t;
      int p = idx >> 3, c4 = (idx & 7) * 4;
      float4 v4 = *(const float4*)(WAg + p * KD + rb + c4);
      sWA[p * 33 + c4 + 0] = v4.x;
      sWA[p * 33 + c4 + 1] = v4.y;
      sWA[p * 33 + c4 + 2] = v4.z;
      sWA[p * 33 + c4 + 3] = v4.w;
    }
    for (int q = 0; q < 8; ++q) {
      int idx = q * 256 + t; int p = idx >> 3, r4 = (idx & 7) * 4;
      *(float4*)&sA[p * 36 + r4] = *(const float4*)(A + p * KD + cb0 + r4);
    }
    for (int q = 0; q < 2; ++q) {
      int idx = q * 256 + t; int p = idx >> 1, j4 = (idx & 1) * 4;
      *(float4*)&sBsl[p * 8 + j4] = *(const float4*)(B + p * UD + m0 + j4);
    }
    __syncthreads();
    const int c = t & 31, q = t >> 5;
    float4 hacc = {0.f, 0.f, 0.f, 0.f};
    float gacc = 0.f;
#pragma unroll 8
    for (int p = 0; p < KD; ++p) {
      float wv = sWA[p * 33 + c];
      float4 a4 = *(const float4*)&sA[p * 36 + 4 * q];
      float bq = sBsl[p * 8 + q];
      hacc.x = fmaf(a4.x, wv, hacc.x);
      hacc.y = fmaf(a4.y, wv, hacc.y);
      hacc.z = fmaf(a4.z, wv, hacc.z);
      hacc.w = fmaf(a4.w, wv, hacc.w);
      gacc = fmaf(bq, wv, gacc);
    }
    float* Hm = ws + OFF_H;
    float* Gm = ws + OFF_G;
    Hm[(cb0 + 4*q + 0) * KD + rb + c] = hacc.x;
    Hm[(cb0 + 4*q + 1) * KD + rb + c] = hacc.y;
    Hm[(cb0 + 4*q + 2) * KD + rb + c] = hacc.z;
    Hm[(cb0 + 4*q + 3) * KD + rb + c] = hacc.w;
    Gm[(m0 + q) * KD + rb + c] = gacc;
  }
}

__global__ __launch_bounds__(256) void k_ph3(float* __restrict__ ws, int last)
{
  const int u = blockIdx.x, t = threadIdx.x;
  const int sb = u & 7, hb = u >> 3;
  const int cb2 = sb * 32, rb2 = hb * 32;
  float* V  = ws + OFF_V;
  float* Hm = ws + OFF_H;
  float* Gm = ws + OFF_G;

  __shared__ float sMI_[64 * 65];
  __shared__ float sGb [64 * 36];
  __shared__ float sGc [64 * 36];
  __shared__ float sKs [64 * 33];
  __shared__ float sZ[64];
  __shared__ float sQd[32];
  __shared__ float sRed[8 * 36];

  for (int q = 0; q < 16; ++q) { int idx = q * 256 + t; int row = idx >> 6, col = idx & 63; sMI_[row * 65 + col] = ws[OFF_MI + idx]; }
  for (int q = 0; q < 2; ++q) {
    int idx = q * 256 + t; int m = idx >> 3, c4 = (idx & 7) * 4;
    float4 g4 = *(const float4*)(Gm + m * KD + cb2 + c4);
    sGb[m * 36 + c4 + 0] = g4.x; sGb[m * 36 + c4 + 1] = g4.y;
    sGb[m * 36 + c4 + 2] = g4.z; sGb[m * 36 + c4 + 3] = g4.w;
  }
  for (int q = 0; q < 2; ++q) {
    int idx = q * 256 + t; int m = idx >> 3, c4 = (idx & 7) * 4;
    float4 g4 = *(const float4*)(Gm + m * KD + rb2 + c4);
    sGc[m * 36 + c4 + 0] = g4.x; sGc[m * 36 + c4 + 1] = g4.y;
    sGc[m * 36 + c4 + 2] = g4.z; sGc[m * 36 + c4 + 3] = g4.w;
  }
  if (t < 64) sZ[t] = ws[OFF_Z + t];
  if (t < 32) sQd[t] = ws[OFF_QD + rb2 + t];
  __syncthreads();
  {
    const int m = t & 63, wv = t >> 6;
    float k0=0,k1=0,k2=0,k3=0,k4=0,k5=0,k6=0,k7=0;
#pragma unroll 4
    for (int p = 0; p < UD; ++p) {
      float mi = sMI_[m * 65 + p];
      float4 ga  = *(const float4*)&sGb[p * 36 + wv * 8 + 0];
      float4 gb2 = *(const float4*)&sGb[p * 36 + wv * 8 + 4];
      k0 = fmaf(mi, ga.x, k0); k1 = fmaf(mi, ga.y, k1);
      k2 = fmaf(mi, ga.z, k2); k3 = fmaf(mi, ga.w, k3);
      k4 = fmaf(mi, gb2.x, k4); k5 = fmaf(mi, gb2.y, k5);
      k6 = fmaf(mi, gb2.z, k6); k7 = fmaf(mi, gb2.w, k7);
    }
    sKs[m * 33 + wv * 8 + 0] = k0; sKs[m * 33 + wv * 8 + 1] = k1;
    sKs[m * 33 + wv * 8 + 2] = k2; sKs[m * 33 + wv * 8 + 3] = k3;
    sKs[m * 33 + wv * 8 + 4] = k4; sKs[m * 33 + wv * 8 + 5] = k5;
    sKs[m * 33 + wv * 8 + 6] = k6; sKs[m * 33 + wv * 8 + 7] = k7;
    if (last && hb == 0) {
      float* K0 = ws + OFF_K0;
      K0[m * KD + cb2 + wv * 8 + 0] = k0; K0[m * KD + cb2 + wv * 8 + 1] = k1;
      K0[m * KD + cb2 + wv * 8 + 2] = k2; K0[m * KD + cb2 + wv * 8 + 3] = k3;
      K0[m * KD + cb2 + wv * 8 + 4] = k4; K0[m * KD + cb2 + wv * 8 + 5] = k5;
      K0[m * KD + cb2 + wv * 8 + 6] = k6; K0[m * KD + cb2 + wv * 8 + 7] = k7;
    }
  }
  __syncthreads();
  {
    const int c = t & 31, q = t >> 5;
    float a0 = 0.f, a1 = 0.f, a2 = 0.f, a3 = 0.f;
#pragma unroll 8
    for (int m = 0; m < UD; ++m) {
      float4 g4 = *(const float4*)&sGc[m * 36 + 4 * q];
      float km = sKs[m * 33 + c];
      a0 = fmaf(g4.x, km, a0); a1 = fmaf(g4.y, km, a1);
      a2 = fmaf(g4.z, km, a2); a3 = fmaf(g4.w, km, a3);
    }
    const int cc = cb2 + c;
    int r = rb2 + 4 * q;
    float h0 = Hm[(r+0) * KD + cc], h1 = Hm[(r+1) * KD + cc];
    float h2 = Hm[(r+2) * KD + cc], h3 = Hm[(r+3) * KD + cc];
    V[(r+0) * KD + cc] = h0 - a0 + ((r+0 == cc) ? sQd[4*q+0] : 0.f);
    V[(r+1) * KD + cc] = h1 - a1 + ((r+1 == cc) ? sQd[4*q+1] : 0.f);
    V[(r+2) * KD + cc] = h2 - a2 + ((r+2 == cc) ? sQd[4*q+2] : 0.f);
    V[(r+3) * KD + cc] = h3 - a3 + ((r+3 == cc) ? sQd[4*q+3] : 0.f);
  }
  if (hb == 0) {
    int c = t & 31, part = t >> 5;
    float acc2 = 0.f;
#pragma unroll
    for (int m = part * 8; m < part * 8 + 8; ++m) acc2 = fmaf(sKs[m * 33 + c], sZ[m], acc2);
    sRed[part * 36 + c] = acc2;
    __syncthreads();
    if (t < 32)  {
      float s2 = 0.f;
#pragma unroll
      for (int pt = 0; pt < 8; ++pt) s2 += sRed[pt * 36 + t];
      ws[OFF_v + cb2 + t] = ws[OFF_ATV + cb2 + t] - s2 + ws[OFF_QG + cb2 + t];
    }
  }
}

__global__ __launch_bounds__(256) void k_fin(
    const float* __restrict__ W, const float* __restrict__ bphi,
    float* __restrict__ ws)
{
  const int w = blockIdx.x, t = threadIdx.x;
  const float* K0 = ws + OFF_K0;
  if (w >= 1 && t < 128) {
    int j = t & 63, kk = 2 * (w - 1) + (t >> 6);
    float acc = 0.f;
#pragma unroll 8
    for (int i = 0; i < KD; ++i) acc = fmaf(K0[j * KD + i], W[i * XD + kk], acc);
    ws[OFF_NKT + kk * UD + j] = -acc;
  }
  if (w == 0 && t < UD) {
    float acc = 0.f;
#pragma unroll 8
    for (int i = 0; i < KD; ++i) acc = fmaf(K0[t * KD + i], bphi[i], acc);
    ws[OFF_CV + t] = ws[OFF_KV + t] - acc;
  }
}

__global__ __launch_bounds__(256) void k_batch(const float* __restrict__ x0,
                                               const float* __restrict__ ws,
                                               float* __restrict__ out)
{
  __shared__ float kt[XD][UD];
  __shared__ float cvs[UD];
  const int t = threadIdx.x;
  {
    const float4* src = (const float4*)(ws + OFF_NKT);
    float4* dst = (float4*)kt;
#pragma unroll
    for (int idx = 0; idx < (XD * UD / 4) / 256; ++idx)
      dst[t + idx * 256] = src[t + idx * 256];
  }
  if (t < UD) cvs[t] = ws[OFF_CV + t];
  __syncthreads();

  const int ty = t >> 4, tx = t & 15;
  const long r0 = (long)blockIdx.x * 64 + ty * 4;
  const float* xp = x0 + r0 * XD;

#define FMA4(acc, s, f4)                      \
  acc.x = fmaf((s), (f4).x, acc.x);           \
  acc.y = fmaf((s), (f4).y, acc.y);           \
  acc.z = fmaf((s), (f4).z, acc.z);           \
  acc.w = fmaf((s), (f4).w, acc.w);

  float4 acc0 = {0,0,0,0}, acc1 = {0,0,0,0}, acc2 = {0,0,0,0}, acc3 = {0,0,0,0};
#pragma unroll 2
  for (int k = 0; k < XD; k += 4) {
    float4 x_0 = *(const float4*)(xp + 0 * XD + k);
    float4 x_1 = *(const float4*)(xp + 1 * XD + k);
    float4 x_2 = *(const float4*)(xp + 2 * XD + k);
    float4 x_3 = *(const float4*)(xp + 3 * XD + k);
    float4 k_0 = *(const float4*)&kt[k + 0][tx * 4];
    float4 k_1 = *(const float4*)&kt[k + 1][tx * 4];
    float4 k_2 = *(const float4*)&kt[k + 2][tx * 4];
    float4 k_3 = *(const float4*)&kt[k + 3][tx * 4];
    FMA4(acc0, x_0.x, k_0) FMA4(acc0, x_0.y, k_1) FMA4(acc0, x_0.z, k_2) FMA4(acc0, x_0.w, k_3)
    FMA4(acc1, x_1.x, k_0) FMA4(acc1, x_1.y, k_1) FMA4(acc1, x_1.z, k_2) FMA4(acc1, x_1.w, k_3)
    FMA4(acc2, x_2.x, k_0) FMA4(acc2, x_2.y, k_1) FMA4(acc2, x_2.z, k_2) FMA4(acc2, x_2.w, k_3)
    FMA4(acc3, x_3.x, k_0) FMA4(acc3, x_3.y, k_1) FMA4(acc3, x_3.z, k_2) FMA4(acc3, x_3.w, k_3)
  }
  float4 cq = *(float4*)&cvs[tx * 4];
  acc0.x += cq.x; acc0.y += cq.y; acc0.z += cq.z; acc0.w += cq.w;
  acc1.x += cq.x; acc1.y += cq.y; acc1.z += cq.z; acc1.w += cq.w;
  acc2.x += cq.x; acc2.y += cq.y; acc2.z += cq.z; acc2.w += cq.w;
  acc3.x += cq.x; acc3.y += cq.y; acc3.z += cq.z; acc3.w += cq.w;
  *(float4*)(out + (r0 + 0) * UD + tx * 4) = acc0;
  *(float4*)(out + (r0 + 1) * UD + tx * 4) = acc1;
  *(float4*)(out + (r0 + 2) * UD + tx * 4) = acc2;
  *(float4*)(out + (r0 + 3) * UD + tx * 4) = acc3;
}

extern "C" void kernel_launch(void* const* d_in, const int* in_sizes, int n_in,
                              void* d_out, int out_size, void* d_ws, size_t ws_size,
                              hipStream_t stream) {
  const float* x0   = (const float*)d_in[0];
  const float* Wp   = (const float*)d_in[1];
  const float* bphi = (const float*)d_in[2];
  const float* xg   = (const float*)d_in[3];
  const float* A    = (const float*)d_in[4];
  const float* B    = (const float*)d_in[5];
  const float* ql   = (const float*)d_in[6];
  const float* rl   = (const float*)d_in[7];
  float* ws  = (float*)d_ws;
  float* out = (float*)d_out;

  double* base = (double*)d_ws + DBASE;
  double* Em[3] = { base + 0*DBUF, base + 3*DBUF, base + 6*DBUF };
  double* Gm[3] = { base + 1*DBUF, base + 4*DBUF, base + 7*DBUF };
  double* Hm[3] = { base + 2*DBUF, base + 5*DBUF, base + 8*DBUF };
  double* Wb  = base + 9*DBUF;
  double* Pb  = base + 10*DBUF;
  double* T1b = base + 11*DBUF;
  double* T2b = base + 12*DBUF;
  double* X3b = base + 13*DBUF;
  double* MB  = base + 14*DBUF;
  double* B64 = MB;
  double* Bs64= MB + 16384;
  double* ev[3] = { MB + 32768, MB + 33280, MB + 33792 };
  double* hv[3] = { MB + 33024, MB + 33536, MB + 34048 };
  double* q1  = MB + 34304;
  double* w12 = MB + 34560;
  double* u1  = MB + 34816;
  double* u2  = MB + 35072;
  double* t5  = MB + 35328;

  GJ gz{}; VJ vz{};

  hipLaunchKernelGGL(k_init, dim3(5), dim3(256), 0, stream, Wp, bphi, xg, ql, rl, ws);
  hipLaunchKernelGGL(k_cvt, dim3(256), dim3(256), 0, stream, A, B, ws);
  // G1 = S = Bs @ B^T
  {
    GJ g0{ Bs64, B64, nullptr, Gm[0], 64, 1, 1, 64, 64, 0 };
    hipLaunchKernelGGL(k_gemm64, dim3(64), dim3(256), 0, stream, g0, gz, gz, 1, vz, vz, vz);
  }

  auto comp = [&](int ia, int ib, int io) {
    double *Ea = Em[ia], *Ga = Gm[ia], *Ha = Hm[ia], *ea = ev[ia], *ha = hv[ia];
    double *Eb = Em[ib], *Gb = Gm[ib], *Hb = Hm[ib], *eb = ev[ib], *hb = hv[ib];
    double *Eo = Em[io], *Go = Gm[io], *Ho = Hm[io], *eo = ev[io], *ho = hv[io];
    // L1: Y = I + Ga@Hb -> Wb ; q1 = Ga@hb
    {
      GJ g0{ Ga, Hb, nullptr, Wb, 256, 1, 256, 1, 256, 1 };
      VJ v0{ Ga, hb, nullptr, q1, 256, 1, 1.0 };
      hipLaunchKernelGGL(k_gemm64, dim3(65), dim3(256), 0, stream, g0, gz, gz, 1, v0, vz, vz);
    }
    // L2: Wb = inv(Wb)
    hipLaunchKernelGGL(k_inv64, dim3(1), dim3(1024), 0, stream, Wb);
    // L3: P = W@Ea ; T1 = W@Ga ; w12 = -W@q1 ; u1 = W@ea
    {
      GJ g0{ Wb, Ea, nullptr, Pb, 256, 1, 256, 1, 256, 0 };
      GJ g1{ Wb, Ga, nullptr, T1b, 256, 1, 256, 1, 256, 0 };
      VJ v0{ Wb, q1, nullptr, w12, 256, 1, -1.0 };
      VJ v1{ Wb, ea, nullptr, u1, 256, 1, 1.0 };
      hipLaunchKernelGGL(k_gemm64, dim3(130), dim3(256), 0, stream, g0, g1, gz, 2, v0, v1, vz);
    }
    // L4: Eo = Eb@P ; T2 = Eb@T1 ; X3 = Hb@P ; eo = Eb@w12+eb ; u2 = Hb@u1 ; t5 = P^T@hb+ha
    {
      GJ g0{ Eb, Pb, nullptr, Eo, 256, 1, 256, 1, 256, 0 };
      GJ g1{ Eb, T1b, nullptr, T2b, 256, 1, 256, 1, 256, 0 };
      GJ g2{ Hb, Pb, nullptr, X3b, 256, 1, 256, 1, 256, 0 };
      VJ v0{ Eb, w12, eb, eo, 256, 1, 1.0 };
      VJ v1{ Hb, u1, nullptr, u2, 256, 1, 1.0 };
      VJ v2{ Pb, hb, ha, t5, 1, 256, 1.0 };
      hipLaunchKernelGGL(k_gemm64, dim3(195), dim3(256), 0, stream, g0, g1, g2, 3, v0, v1, v2);
    }
    // L5: Go = Gb + T2@Eb^T ; Ho = Ha + Ea^T@X3 ; ho = Ea^T@u2 + t5
    {
      GJ g0{ T2b, Eb, Gb, Go, 256, 1, 1, 256, 256, 0 };
      GJ g1{ Ea, X3b, Ha, Ho, 1, 256, 256, 1, 256, 0 };
      VJ v0{ Ea, u2, t5, ho, 1, 256, 1.0 };
      hipLaunchKernelGGL(k_gemm64, dim3(129), dim3(256), 0, stream, g0, g1, gz, 2, v0, vz, vz);
    }
  };

  // T2 -> T4 -> T8 -> T16 -> T32 -> T64 -> T72 -> T128 -> T200
  comp(0, 0, 1);   // T2
  comp(1, 1, 0);   // T4
  comp(0, 0, 1);   // T8
  comp(1, 1, 2);   // T16
  comp(2, 2, 0);   // T32
  comp(0, 0, 2);   // T64
  comp(2, 1, 0);   // T72  = T64 o T8
  comp(2, 2, 1);   // T128 = T64 o T64
  comp(1, 0, 2);   // T200 = T128 o T72

  // V_199 = H(T200), v_199 = -h(T200); then the 200th scan call (verified kernels)
  hipLaunchKernelGGL(k_fin2, dim3(256), dim3(256), 0, stream, ws);
  hipLaunchKernelGGL(k_ph1, dim3(64), dim3(256), 0, stream, A, B, ws);
  hipLaunchKernelGGL(k_ph2, dim3(65), dim3(256), 0, stream, A, B, ws, 1);
  hipLaunchKernelGGL(k_ph3, dim3(64), dim3(256), 0, stream, ws, 1);
  hipLaunchKernelGGL(k_fin, dim3(65), dim3(256), 0, stream, Wp, bphi, ws);
  int rows = in_sizes[0] / XD;
  int nblk = rows / 64;
  hipLaunchKernelGGL(k_batch, dim3(nblk), dim3(256), 0, stream, x0, ws, out);
}

// Round 10
// 2548.062 us; speedup vs baseline: 6.8669x; 6.8669x over previous
//
#include <hip/hip_runtime.h>
#include <math.h>

#define KD 256
#define UD 64
#define XD 128

// ws float offsets (single-step machinery, unchanged from R6)
#define OFF_V     0
#define OFF_WA    65536
#define OFF_H     131072
#define OFF_G     196608
#define OFF_K0    212992
#define OFF_MI    229376
#define OFF_MP    233472
#define OFF_v     266240
#define OFF_ATV   266496
#define OFF_Z     266752
#define OFF_QG    266816
#define OFF_QD    267072
#define OFF_RD    267328
#define OFF_KV    267392
#define OFF_CV    267456
#define OFF_NKT   267520
// SDA fp64 buffers start at float index 278528 (= double index 139264)
#define DBASE     139264
#define DBUF      65536

__device__ __forceinline__ void inv4(float* D) {
#pragma unroll
  for (int p = 0; p < 4; ++p) {
    float ip = 1.0f / D[p * 4 + p];
#pragma unroll
    for (int i2 = 0; i2 < 4; ++i2)
      if (i2 != p) {
        float f = D[i2 * 4 + p] * ip;
#pragma unroll
        for (int j = 0; j < 4; ++j)
          if (j != p) D[i2 * 4 + j] -= f * D[p * 4 + j];
        D[i2 * 4 + p] = -f;
      }
#pragma unroll
    for (int j = 0; j < 4; ++j)
      if (j != p) D[p * 4 + j] *= ip;
    D[p * 4 + p] = ip;
  }
}

__device__ __forceinline__ void inv4d(double* D) {
#pragma unroll
  for (int p = 0; p < 4; ++p) {
    double ip = 1.0 / D[p * 4 + p];
#pragma unroll
    for (int i2 = 0; i2 < 4; ++i2)
      if (i2 != p) {
        double f = D[i2 * 4 + p] * ip;
#pragma unroll
        for (int j = 0; j < 4; ++j)
          if (j != p) D[i2 * 4 + j] -= f * D[p * 4 + j];
        D[i2 * 4 + p] = -f;
      }
#pragma unroll
    for (int j = 0; j < 4; ++j)
      if (j != p) D[p * 4 + j] *= ip;
    D[p * 4 + p] = ip;
  }
}

#define R16(OP) OP(0) OP(1) OP(2) OP(3) OP(4) OP(5) OP(6) OP(7) OP(8) OP(9) OP(10) OP(11) OP(12) OP(13) OP(14) OP(15)

// ================= init =================
__global__ __launch_bounds__(256) void k_init(
    const float* __restrict__ W, const float* __restrict__ bphi,
    const float* __restrict__ xg, const float* __restrict__ qlog,
    const float* __restrict__ rlog, float* __restrict__ ws)
{
  const int w = blockIdx.x, t = threadIdx.x;
  if (w < 4 && t < 64) {
    int i = w * 64 + t;
    float acc = 0.f;
    for (int p = 0; p < XD; ++p) acc = fmaf(W[i * XD + p], xg[p], acc);
    float g = acc + bphi[i];
    float qd = expf(qlog[i]);
    ws[OFF_QD + i] = qd; ws[OFF_QG + i] = qd * g; ws[OFF_v + i] = qd * g;
  }
  if (w == 4 && t < UD) ws[OFF_RD + t] = expf(rlog[t]);
}

// ================= cvt: fp64 seeds =================
__global__ __launch_bounds__(256) void k_cvt(
    const float* __restrict__ A, const float* __restrict__ B, float* __restrict__ ws)
{
  double* base = (double*)ws + DBASE;
  double* E1 = base + 0 * DBUF;
  double* H1 = base + 2 * DBUF;
  double* MB = base + 14 * DBUF;
  double* B64 = MB;
  double* Bs64 = MB + 16384;
  double* eA = MB + 32768;
  double* hA = MB + 33024;
  int id = blockIdx.x * 256 + threadIdx.x;   // 0..65535
  E1[id] = (double)A[id];
  int i = id >> 8, j = id & 255;
  H1[id] = (i == j) ? (double)ws[OFF_QD + i] : 0.0;
  if (id < 16384) {
    int m = id & 63;
    B64[id] = (double)B[id];
    Bs64[id] = (double)B[id] / (double)ws[OFF_RD + m];
  }
  if (id < 256) {
    eA[id] = 0.0;
    hA[id] = -(double)ws[OFF_QG + id];
  }
}

// ================= fp64 batched GEMM/matvec job kernel =================
struct GJ { const double* A; const double* B; const double* C; double* O;
            int sA0, sA1, sB0, sB1, K, addI; };
struct VJ { const double* M1; const double* x; const double* a; double* o;
            int s0, s1; double sgn; };

__global__ __launch_bounds__(256) void k_gemm64(GJ g0, GJ g1, GJ g2, int ng,
                                                VJ v0, VJ v1, VJ v2)
{
  __shared__ double As[32 * 33];
  __shared__ double Bs[32 * 33];
  __shared__ double xs[256];
  const int wg = blockIdx.x, t = threadIdx.x;
  if (wg < ng * 64) {
    GJ j = (wg < 64) ? g0 : (wg < 128) ? g1 : g2;
    const int w2 = wg & 63;
    const int tm0 = (w2 >> 3) * 32, tn0 = (w2 & 7) * 32;
    const int rq = t >> 5, c = t & 31;
    double a0 = 0, a1 = 0, a2 = 0, a3 = 0;
    for (int k0 = 0; k0 < j.K; k0 += 32) {
#pragma unroll
      for (int q = 0; q < 4; ++q) {
        int lin = q * 256 + t; int r = lin >> 5, kk = lin & 31;
        As[r * 33 + kk] = j.A[(long)(tm0 + r) * j.sA0 + (long)(k0 + kk) * j.sA1];
        Bs[r * 33 + kk] = j.B[(long)(k0 + r) * j.sB0 + (long)(tn0 + kk) * j.sB1];
      }
      __syncthreads();
#pragma unroll 8
      for (int kk = 0; kk < 32; ++kk) {
        double b = Bs[kk * 33 + c];
        a0 = fma(As[(rq * 4 + 0) * 33 + kk], b, a0);
        a1 = fma(As[(rq * 4 + 1) * 33 + kk], b, a1);
        a2 = fma(As[(rq * 4 + 2) * 33 + kk], b, a2);
        a3 = fma(As[(rq * 4 + 3) * 33 + kk], b, a3);
      }
      __syncthreads();
    }
    const int n = tn0 + c;
    double av[4] = {a0, a1, a2, a3};
#pragma unroll
    for (int i2 = 0; i2 < 4; ++i2) {
      int m = tm0 + rq * 4 + i2;
      double v = av[i2];
      if (j.C) v += j.C[m * 256 + n];
      if (j.addI && m == n) v += 1.0;
      j.O[m * 256 + n] = v;
    }
  } else {
    const int vi = wg - ng * 64;
    VJ j = (vi == 0) ? v0 : (vi == 1) ? v1 : v2;
    xs[t] = j.x[t];
    __syncthreads();
    double acc = 0;
#pragma unroll 8
    for (int k2 = 0; k2 < 256; ++k2)
      acc = fma(j.M1[(long)t * j.s0 + (long)k2 * j.s1], xs[k2], acc);
    double o = j.sgn * acc;
    if (j.a) o += j.a[t];
    j.o[t] = o;
  }
}

// ================= fp64 256x256 inverse: one PANEL step (64 WGs, ping-pong) ====
// Blocked unpivoted Gauss-Jordan, panel width 64, 4 launches per inverse.
// R10 FIX vs R9: the trailing update is Y - C @ U  (= Y - C D^-1 R), matching
// the verified R8 k_inv64 (Pc x Rw). R9 wrongly used L @ U = C D^-2 R.
__global__ __launch_bounds__(256) void k_pinv(const double* __restrict__ Yc,
                                              double* __restrict__ Yn, int pk)
{
  const int w = blockIdx.x, t = threadIdx.x;
  const int bi = w >> 3, bj = w & 7;       // 32-wide tile block coords
  const int p0 = pk * 64, pb = pk * 2;     // panel col start / block index
  const int r0 = bi * 32, c0 = bj * 32;

  __shared__ double sDI[64 * 65];
  __shared__ double sC [32 * 66];
  __shared__ double sR [64 * 34];
  __shared__ double sL [32 * 66];
  __shared__ double sU [64 * 34];
  __shared__ double sPR[4 * 68];
  __shared__ double sF [64 * 5];

  // stage C (own rows x panel cols) and R (panel rows x own cols)
  for (int q = 0; q < 8; ++q) { int lin = q * 256 + t; int r = lin >> 6, m = lin & 63; sC[r * 66 + m] = Yc[(r0 + r) * 256 + p0 + m]; }
  for (int q = 0; q < 8; ++q) { int lin = q * 256 + t; int m = lin >> 5, c = lin & 31; sR[m * 34 + c] = Yc[(p0 + m) * 256 + c0 + c]; }

  // ---- fp64 rank-4 GJ inverse of D (redundant per WG) ----
  const int i = t & 63, cg = t >> 6;
  double rr[16];
#pragma unroll
  for (int q = 0; q < 16; ++q) rr[q] = Yc[(p0 + i) * 256 + p0 + cg * 16 + q];
  for (int k = 0; k < 16; ++k) {
    const int prw = i - 4 * k;
    const bool inblk = (unsigned)prw < 4u;
    if (inblk) {
#pragma unroll
      for (int q = 0; q < 16; ++q) sPR[prw * 68 + cg * 16 + q] = rr[q];
    }
    if (cg == (k >> 2)) {
      const int b = (k & 3) * 4;
      sF[i * 5 + 0] = rr[b + 0]; sF[i * 5 + 1] = rr[b + 1];
      sF[i * 5 + 2] = rr[b + 2]; sF[i * 5 + 3] = rr[b + 3];
    }
    __syncthreads();
    double D[16];
#pragma unroll
    for (int q = 0; q < 4; ++q) {
      D[q * 4 + 0] = sPR[q * 68 + 4 * k + 0];
      D[q * 4 + 1] = sPR[q * 68 + 4 * k + 1];
      D[q * 4 + 2] = sPR[q * 68 + 4 * k + 2];
      D[q * 4 + 3] = sPR[q * 68 + 4 * k + 3];
    }
    inv4d(D);
    double f0 = sF[i * 5 + 0], f1 = sF[i * 5 + 1], f2 = sF[i * 5 + 2], f3 = sF[i * 5 + 3];
    double g0, g1, g2, g3;
    if (inblk) {
      g0 = prw == 0 ? D[0] : prw == 1 ? D[4] : prw == 2 ? D[8]  : D[12];
      g1 = prw == 0 ? D[1] : prw == 1 ? D[5] : prw == 2 ? D[9]  : D[13];
      g2 = prw == 0 ? D[2] : prw == 1 ? D[6] : prw == 2 ? D[10] : D[14];
      g3 = prw == 0 ? D[3] : prw == 1 ? D[7] : prw == 2 ? D[11] : D[15];
    } else {
      g0 = f0 * D[0] + f1 * D[4] + f2 * D[8]  + f3 * D[12];
      g1 = f0 * D[1] + f1 * D[5] + f2 * D[9]  + f3 * D[13];
      g2 = f0 * D[2] + f1 * D[6] + f2 * D[10] + f3 * D[14];
      g3 = f0 * D[3] + f1 * D[7] + f2 * D[11] + f3 * D[15];
    }
#pragma unroll
    for (int q = 0; q < 16; ++q) {
      double pr0 = sPR[0 * 68 + cg * 16 + q];
      double pr1 = sPR[1 * 68 + cg * 16 + q];
      double pr2 = sPR[2 * 68 + cg * 16 + q];
      double pr3 = sPR[3 * 68 + cg * 16 + q];
      double n = fma(g0, pr0, fma(g1, pr1, fma(g2, pr2, g3 * pr3)));
      rr[q] = inblk ? n : rr[q] - n;
    }
    if (cg == (k >> 2)) {
      const int b = (k & 3) * 4;
      rr[b + 0] = inblk ? g0 : -g0; rr[b + 1] = inblk ? g1 : -g1;
      rr[b + 2] = inblk ? g2 : -g2; rr[b + 3] = inblk ? g3 : -g3;
    }
    __syncthreads();
  }
#pragma unroll
  for (int q = 0; q < 16; ++q) sDI[i * 65 + cg * 16 + q] = rr[q];
  __syncthreads();

  // ---- L = sC @ sDI (32x64), U = sDI @ sR (64x32) ----
  {
    const int r = t >> 3, u0 = (t & 7) * 8;
    double acc[8];
#pragma unroll
    for (int u = 0; u < 8; ++u) acc[u] = 0.0;
#pragma unroll 4
    for (int m = 0; m < 64; ++m) {
      double cv = sC[r * 66 + m];
#pragma unroll
      for (int u = 0; u < 8; ++u) acc[u] = fma(cv, sDI[m * 65 + u0 + u], acc[u]);
    }
#pragma unroll
    for (int u = 0; u < 8; ++u) sL[r * 66 + u0 + u] = acc[u];
  }
  {
    const int qrow = t >> 2, c4 = (t & 3) * 8;
    double acc[8];
#pragma unroll
    for (int u = 0; u < 8; ++u) acc[u] = 0.0;
#pragma unroll 4
    for (int m = 0; m < 64; ++m) {
      double dv = sDI[qrow * 65 + m];
#pragma unroll
      for (int u = 0; u < 8; ++u) acc[u] = fma(dv, sR[m * 34 + c4 + u], acc[u]);
    }
#pragma unroll
    for (int u = 0; u < 8; ++u) sU[qrow * 34 + c4 + u] = acc[u];
  }
  __syncthreads();

  // ---- write own 32x32 tile of Yn ----
  const bool rip = (bi == pb || bi == pb + 1);
  const bool cip = (bj == pb || bj == pb + 1);
  const int r = t >> 3, cc4 = (t & 7) * 4;
#pragma unroll
  for (int u = 0; u < 4; ++u) {
    const int c = cc4 + u;
    double outv;
    if (rip && cip) {
      outv = sDI[((bi - pb) * 32 + r) * 65 + (bj - pb) * 32 + c];
    } else if (cip) {
      outv = -sL[r * 66 + (bj - pb) * 32 + c];
    } else if (rip) {
      outv = sU[((bi - pb) * 32 + r) * 34 + c];
    } else {
      // trailing: Y - C @ U   (R10 fix: sC, not sL)
      double acc = Yc[(r0 + r) * 256 + c0 + c];
#pragma unroll 8
      for (int q = 0; q < 64; ++q) acc = fma(-sC[r * 66 + q], sU[q * 34 + c], acc);
      outv = acc;
    }
    Yn[(r0 + r) * 256 + c0 + c] = outv;
  }
}

// ================= fin2: V = (float)H_final, vv = -(float)h_final =================
__global__ __launch_bounds__(256) void k_fin2(float* __restrict__ ws)
{
  double* base = (double*)ws + DBASE;
  double* Hf = base + 8 * DBUF;              // SetC.H
  double* hf = base + 14 * DBUF + 34048;     // hC
  int id = blockIdx.x * 256 + threadIdx.x;
  ws[OFF_V + id] = (float)Hf[id];
  if (id < 256) ws[OFF_v + id] = -(float)hf[id];
}

// ================= single Riccati step (verified R6 kernels, unchanged) =================
__global__ __launch_bounds__(256) void k_ph1(
    const float* __restrict__ A, const float* __restrict__ B,
    float* __restrict__ ws)
{
  const int u = blockIdx.x, t = threadIdx.x;
  const int sb = u & 7, hb = u >> 3;
  const int rb = sb * 32, cb0 = hb * 32, m0 = hb * 8;
  float* V   = ws + OFF_V;
  float* WAg = ws + OFF_WA;

  __shared__ float sVt[256 * 36];
  __shared__ float sA [256 * 36];
  __shared__ float sBsl[256 * 8];
  __shared__ float sBr[32 * 64];
  __shared__ float svv[256];
  __shared__ float sVB[32 * 9];
  __shared__ float sRed[8 * 36];

  for (int q = 0; q < 8; ++q) {
    int idx = q * 256 + t; int p = idx >> 3, r4 = (idx & 7) * 4;
    *(float4*)&sVt[p * 36 + r4] = *(const float4*)(V + p * KD + rb + r4);
  }
  for (int q = 0; q < 8; ++q) {
    int idx = q * 256 + t; int p = idx >> 3, r4 = (idx & 7) * 4;
    *(float4*)&sA[p * 36 + r4] = *(const float4*)(A + p * KD + cb0 + r4);
  }
  for (int q = 0; q < 2; ++q) {
    int idx = q * 256 + t; int p = idx >> 1, j4 = (idx & 1) * 4;
    *(float4*)&sBsl[p * 8 + j4] = *(const float4*)(B + p * UD + m0 + j4);
  }
  for (int q = 0; q < 2; ++q) {
    int idx = q * 256 + t; int r = idx >> 4, a4 = (idx & 15) * 4;
    *(float4*)&sBr[r * 64 + a4] = *(const float4*)(B + (rb + r) * UD + a4);
  }
  svv[t] = ws[OFF_v + t];
  __syncthreads();

  const int j = t & 31, rq = t >> 5;
  float4 acc = {0.f, 0.f, 0.f, 0.f};
  float avb0 = 0.f, avb1 = 0.f, avb2 = 0.f, avb3 = 0.f;
  const bool dovb = (j < 8);
#pragma unroll 8
  for (int p = 0; p < KD; ++p) {
    float4 v4 = *(const float4*)&sVt[p * 36 + rq * 4];
    float a = sA[p * 36 + j];
    acc.x = fmaf(v4.x, a, acc.x);
    acc.y = fmaf(v4.y, a, acc.y);
    acc.z = fmaf(v4.z, a, acc.z);
    acc.w = fmaf(v4.w, a, acc.w);
    if (dovb) {
      float b = sBsl[p * 8 + j];
      avb0 = fmaf(v4.x, b, avb0);
      avb1 = fmaf(v4.y, b, avb1);
      avb2 = fmaf(v4.z, b, avb2);
      avb3 = fmaf(v4.w, b, avb3);
    }
  }
  WAg[(rb + 4 * rq + 0) * KD + cb0 + j] = acc.x;
  WAg[(rb + 4 * rq + 1) * KD + cb0 + j] = acc.y;
  WAg[(rb + 4 * rq + 2) * KD + cb0 + j] = acc.z;
  WAg[(rb + 4 * rq + 3) * KD + cb0 + j] = acc.w;
  if (dovb) {
    sVB[(4 * rq + 0) * 9 + j] = avb0;
    sVB[(4 * rq + 1) * 9 + j] = avb1;
    sVB[(4 * rq + 2) * 9 + j] = avb2;
    sVB[(4 * rq + 3) * 9 + j] = avb3;
  }
  if (sb == 0) {
    int c = t & 31, part = t >> 5;
    float acc2 = 0.f;
#pragma unroll 8
    for (int p = part * 32; p < part * 32 + 32; ++p) acc2 = fmaf(sA[p * 36 + c], svv[p], acc2);
    sRed[part * 36 + c] = acc2;
  }
  if (sb == 1 && t < 64) {
    int jz = t & 7, part = t >> 3;
    float acc2 = 0.f;
#pragma unroll 8
    for (int p = part * 32; p < part * 32 + 32; ++p) acc2 = fmaf(sBsl[p * 8 + jz], svv[p], acc2);
    sRed[part * 36 + jz] = acc2;
  }
  __syncthreads();
  {
    int a = t & 63, j2 = (t >> 6) * 2;
    float mp0 = 0.f, mp1 = 0.f;
#pragma unroll 8
    for (int r = 0; r < 32; ++r) {
      float bv = sBr[r * 64 + a];
      mp0 = fmaf(bv, sVB[r * 9 + j2 + 0], mp0);
      mp1 = fmaf(bv, sVB[r * 9 + j2 + 1], mp1);
    }
    ws[OFF_MP + sb * 4096 + a * 64 + m0 + j2 + 0] = mp0;
    ws[OFF_MP + sb * 4096 + a * 64 + m0 + j2 + 1] = mp1;
  }
  if (sb == 0 && t < 32) {
    float a2 = 0.f;
#pragma unroll
    for (int pt = 0; pt < 8; ++pt) a2 += sRed[pt * 36 + t];
    ws[OFF_ATV + cb0 + t] = a2;
  }
  if (sb == 1 && t < 8) {
    float a2 = 0.f;
#pragma unroll
    for (int pt = 0; pt < 8; ++pt) a2 += sRed[pt * 36 + t];
    ws[OFF_Z + m0 + t] = a2;
  }
}

__global__ __launch_bounds__(256) void k_ph2(
    const float* __restrict__ A, const float* __restrict__ B,
    float* __restrict__ ws, int last)
{
  const int w = blockIdx.x, t = threadIdx.x;
  const int u = w - 1;
  float* WAg = ws + OFF_WA;
  float* MI  = ws + OFF_MI;

  __shared__ float sWA[256 * 33];
  __shared__ float sA [256 * 36];
  __shared__ float sBsl[256 * 8];
  __shared__ float scr[608];
  __shared__ float wred[256];

  if (w == 0) {
    float* sPR = scr;
    float* sF  = scr + 280;
    const int i = t & 63, cg = t >> 6;
    const float rdi = ws[OFF_RD + i];
    float rr[16];
    {
      float4 s0 = {0,0,0,0}, s1 = {0,0,0,0}, s2 = {0,0,0,0}, s3 = {0,0,0,0};
#pragma unroll
      for (int sb2 = 0; sb2 < 8; ++sb2) {
        const float* mp = ws + OFF_MP + sb2 * 4096 + i * 64 + cg * 16;
        float4 a0 = *(const float4*)(mp + 0);
        float4 a1 = *(const float4*)(mp + 4);
        float4 a2 = *(const float4*)(mp + 8);
        float4 a3 = *(const float4*)(mp + 12);
        s0.x += a0.x; s0.y += a0.y; s0.z += a0.z; s0.w += a0.w;
        s1.x += a1.x; s1.y += a1.y; s1.z += a1.z; s1.w += a1.w;
        s2.x += a2.x; s2.y += a2.y; s2.z += a2.z; s2.w += a2.w;
        s3.x += a3.x; s3.y += a3.y; s3.z += a3.z; s3.w += a3.w;
      }
      rr[0]=s0.x; rr[1]=s0.y; rr[2]=s0.z; rr[3]=s0.w;
      rr[4]=s1.x; rr[5]=s1.y; rr[6]=s1.z; rr[7]=s1.w;
      rr[8]=s2.x; rr[9]=s2.y; rr[10]=s2.z; rr[11]=s2.w;
      rr[12]=s3.x; rr[13]=s3.y; rr[14]=s3.z; rr[15]=s3.w;
#define DIAG(j) rr[j] += (cg * 16 + j == i) ? rdi : 0.f;
      R16(DIAG)
#undef DIAG
    }
    for (int k = 0; k < 16; ++k) {
      const int prw = i - 4 * k;
      const bool inblk = (unsigned)prw < 4u;
      if (inblk) {
#define ST(j) sPR[prw * 68 + cg * 16 + j] = rr[j];
        R16(ST)
#undef ST
      }
      if (cg == (k >> 2)) {
        switch (k & 3) {
          case 0: sF[i*5+0]=rr[0];  sF[i*5+1]=rr[1];  sF[i*5+2]=rr[2];  sF[i*5+3]=rr[3];  break;
          case 1: sF[i*5+0]=rr[4];  sF[i*5+1]=rr[5];  sF[i*5+2]=rr[6];  sF[i*5+3]=rr[7];  break;
          case 2: sF[i*5+0]=rr[8];  sF[i*5+1]=rr[9];  sF[i*5+2]=rr[10]; sF[i*5+3]=rr[11]; break;
          default:sF[i*5+0]=rr[12]; sF[i*5+1]=rr[13]; sF[i*5+2]=rr[14]; sF[i*5+3]=rr[15]; break;
        }
      }
      __syncthreads();
      float D[16];
#pragma unroll
      for (int q = 0; q < 4; ++q) {
        D[q*4+0] = sPR[q*68 + 4*k + 0];
        D[q*4+1] = sPR[q*68 + 4*k + 1];
        D[q*4+2] = sPR[q*68 + 4*k + 2];
        D[q*4+3] = sPR[q*68 + 4*k + 3];
      }
      inv4(D);
      float f0 = sF[i*5+0], f1 = sF[i*5+1], f2 = sF[i*5+2], f3 = sF[i*5+3];
      float g0, g1, g2, g3;
      if (inblk) {
        g0 = prw==0?D[0]:prw==1?D[4]:prw==2?D[8]:D[12];
        g1 = prw==0?D[1]:prw==1?D[5]:prw==2?D[9]:D[13];
        g2 = prw==0?D[2]:prw==1?D[6]:prw==2?D[10]:D[14];
        g3 = prw==0?D[3]:prw==1?D[7]:prw==2?D[11]:D[15];
      } else {
        g0 = f0*D[0] + f1*D[4] + f2*D[8]  + f3*D[12];
        g1 = f0*D[1] + f1*D[5] + f2*D[9]  + f3*D[13];
        g2 = f0*D[2] + f1*D[6] + f2*D[10] + f3*D[14];
        g3 = f0*D[3] + f1*D[7] + f2*D[11] + f3*D[15];
      }
#define CHUNK(c4)                                                         \
      {                                                                   \
        float4 p0 = *(const float4*)&sPR[0 * 68 + cg * 16 + (c4) * 4];    \
        float4 p1 = *(const float4*)&sPR[1 * 68 + cg * 16 + (c4) * 4];    \
        float4 p2 = *(const float4*)&sPR[2 * 68 + cg * 16 + (c4) * 4];    \
        float4 p3 = *(const float4*)&sPR[3 * 68 + cg * 16 + (c4) * 4];    \
        float n0 = fmaf(g0,p0.x, fmaf(g1,p1.x, fmaf(g2,p2.x, g3*p3.x)));  \
        float n1 = fmaf(g0,p0.y, fmaf(g1,p1.y, fmaf(g2,p2.y, g3*p3.y)));  \
        float n2 = fmaf(g0,p0.z, fmaf(g1,p1.z, fmaf(g2,p2.z, g3*p3.z)));  \
        float n3 = fmaf(g0,p0.w, fmaf(g1,p1.w, fmaf(g2,p2.w, g3*p3.w)));  \
        if (inblk) { rr[(c4)*4+0]=n0; rr[(c4)*4+1]=n1; rr[(c4)*4+2]=n2; rr[(c4)*4+3]=n3; } \
        else { rr[(c4)*4+0]-=n0; rr[(c4)*4+1]-=n1; rr[(c4)*4+2]-=n2; rr[(c4)*4+3]-=n3; }   \
      }
      CHUNK(0) CHUNK(1) CHUNK(2) CHUNK(3)
#undef CHUNK
      if (cg == (k >> 2)) {
        switch (k & 3) {
          case 0: rr[0] = inblk? g0:-g0; rr[1] = inblk? g1:-g1; rr[2] = inblk? g2:-g2; rr[3] = inblk? g3:-g3; break;
          case 1: rr[4] = inblk? g0:-g0; rr[5] = inblk? g1:-g1; rr[6] = inblk? g2:-g2; rr[7] = inblk? g3:-g3; break;
          case 2: rr[8] = inblk? g0:-g0; rr[9] = inblk? g1:-g1; rr[10]= inblk? g2:-g2; rr[11]= inblk? g3:-g3; break;
          default:rr[12]= inblk? g0:-g0; rr[13]= inblk? g1:-g1; rr[14]= inblk? g2:-g2; rr[15]= inblk? g3:-g3; break;
        }
      }
      __syncthreads();
    }
    *(float4*)(MI + i * 64 + cg * 16 + 0)  = *(float4*)&rr[0];
    *(float4*)(MI + i * 64 + cg * 16 + 4)  = *(float4*)&rr[4];
    *(float4*)(MI + i * 64 + cg * 16 + 8)  = *(float4*)&rr[8];
    *(float4*)(MI + i * 64 + cg * 16 + 12) = *(float4*)&rr[12];
    if (last) {
      float p2 = 0.f;
#define KV(j) p2 = fmaf(rr[j], ws[OFF_Z + cg * 16 + j], p2);
      R16(KV)
#undef KV
      wred[i * 4 + cg] = p2;
      __syncthreads();
      if (t < 64) ws[OFF_KV + t] = wred[t*4+0] + wred[t*4+1] + wred[t*4+2] + wred[t*4+3];
    }
  } else {
    const int sb = u & 7, hb = u >> 3;
    const int rb = sb * 32, cb0 = hb * 32, m0 = hb * 8;
    for (int q = 0; q < 8; ++q) {
      int idx = q * 256 + t;
      int p = idx >> 3, c4 = (idx & 7) * 4;
      float4 v4 = *(const float4*)(WAg + p * KD + rb + c4);
      sWA[p * 33 + c4 + 0] = v4.x;
      sWA[p * 33 + c4 + 1] = v4.y;
      sWA[p * 33 + c4 + 2] = v4.z;
      sWA[p * 33 + c4 + 3] = v4.w;
    }
    for (int q = 0; q < 8; ++q) {
      int idx = q * 256 + t; int p = idx >> 3, r4 = (idx & 7) * 4;
      *(float4*)&sA[p * 36 + r4] = *(const float4*)(A + p * KD + cb0 + r4);
    }
    for (int q = 0; q < 2; ++q) {
      int idx = q * 256 + t; int p = idx >> 1, j4 = (idx & 1) * 4;
      *(float4*)&sBsl[p * 8 + j4] = *(const float4*)(B + p * UD + m0 + j4);
    }
    __syncthreads();
    const int c = t & 31, q = t >> 5;
    float4 hacc = {0.f, 0.f, 0.f, 0.f};
    float gacc = 0.f;
#pragma unroll 8
    for (int p = 0; p < KD; ++p) {
      float wv = sWA[p * 33 + c];
      float4 a4 = *(const float4*)&sA[p * 36 + 4 * q];
      float bq = sBsl[p * 8 + q];
      hacc.x = fmaf(a4.x, wv, hacc.x);
      hacc.y = fmaf(a4.y, wv, hacc.y);
      hacc.z = fmaf(a4.z, wv, hacc.z);
      hacc.w = fmaf(a4.w, wv, hacc.w);
      gacc = fmaf(bq, wv, gacc);
    }
    float* Hm = ws + OFF_H;
    float* Gm = ws + OFF_G;
    Hm[(cb0 + 4*q + 0) * KD + rb + c] = hacc.x;
    Hm[(cb0 + 4*q + 1) * KD + rb + c] = hacc.y;
    Hm[(cb0 + 4*q + 2) * KD + rb + c] = hacc.z;
    Hm[(cb0 + 4*q + 3) * KD + rb + c] = hacc.w;
    Gm[(m0 + q) * KD + rb + c] = gacc;
  }
}

__global__ __launch_bounds__(256) void k_ph3(float* __restrict__ ws, int last)
{
  const int u = blockIdx.x, t = threadIdx.x;
  const int sb = u & 7, hb = u >> 3;
  const int cb2 = sb * 32, rb2 = hb * 32;
  float* V  = ws + OFF_V;
  float* Hm = ws + OFF_H;
  float* Gm = ws + OFF_G;

  __shared__ float sMI_[64 * 65];
  __shared__ float sGb [64 * 36];
  __shared__ float sGc [64 * 36];
  __shared__ float sKs [64 * 33];
  __shared__ float sZ[64];
  __shared__ float sQd[32];
  __shared__ float sRed[8 * 36];

  for (int q = 0; q < 16; ++q) { int idx = q * 256 + t; int row = idx >> 6, col = idx & 63; sMI_[row * 65 + col] = ws[OFF_MI + idx]; }
  for (int q = 0; q < 2; ++q) {
    int idx = q * 256 + t; int m = idx >> 3, c4 = (idx & 7) * 4;
    float4 g4 = *(const float4*)(Gm + m * KD + cb2 + c4);
    sGb[m * 36 + c4 + 0] = g4.x; sGb[m * 36 + c4 + 1] = g4.y;
    sGb[m * 36 + c4 + 2] = g4.z; sGb[m * 36 + c4 + 3] = g4.w;
  }
  for (int q = 0; q < 2; ++q) {
    int idx = q * 256 + t; int m = idx >> 3, c4 = (idx & 7) * 4;
    float4 g4 = *(const float4*)(Gm + m * KD + rb2 + c4);
    sGc[m * 36 + c4 + 0] = g4.x; sGc[m * 36 + c4 + 1] = g4.y;
    sGc[m * 36 + c4 + 2] = g4.z; sGc[m * 36 + c4 + 3] = g4.w;
  }
  if (t < 64) sZ[t] = ws[OFF_Z + t];
  if (t < 32) sQd[t] = ws[OFF_QD + rb2 + t];
  __syncthreads();
  {
    const int m = t & 63, wv = t >> 6;
    float k0=0,k1=0,k2=0,k3=0,k4=0,k5=0,k6=0,k7=0;
#pragma unroll 4
    for (int p = 0; p < UD; ++p) {
      float mi = sMI_[m * 65 + p];
      float4 ga  = *(const float4*)&sGb[p * 36 + wv * 8 + 0];
      float4 gb2 = *(const float4*)&sGb[p * 36 + wv * 8 + 4];
      k0 = fmaf(mi, ga.x, k0); k1 = fmaf(mi, ga.y, k1);
      k2 = fmaf(mi, ga.z, k2); k3 = fmaf(mi, ga.w, k3);
      k4 = fmaf(mi, gb2.x, k4); k5 = fmaf(mi, gb2.y, k5);
      k6 = fmaf(mi, gb2.z, k6); k7 = fmaf(mi, gb2.w, k7);
    }
    sKs[m * 33 + wv * 8 + 0] = k0; sKs[m * 33 + wv * 8 + 1] = k1;
    sKs[m * 33 + wv * 8 + 2] = k2; sKs[m * 33 + wv * 8 + 3] = k3;
    sKs[m * 33 + wv * 8 + 4] = k4; sKs[m * 33 + wv * 8 + 5] = k5;
    sKs[m * 33 + wv * 8 + 6] = k6; sKs[m * 33 + wv * 8 + 7] = k7;
    if (last && hb == 0) {
      float* K0 = ws + OFF_K0;
      K0[m * KD + cb2 + wv * 8 + 0] = k0; K0[m * KD + cb2 + wv * 8 + 1] = k1;
      K0[m * KD + cb2 + wv * 8 + 2] = k2; K0[m * KD + cb2 + wv * 8 + 3] = k3;
      K0[m * KD + cb2 + wv * 8 + 4] = k4; K0[m * KD + cb2 + wv * 8 + 5] = k5;
      K0[m * KD + cb2 + wv * 8 + 6] = k6; K0[m * KD + cb2 + wv * 8 + 7] = k7;
    }
  }
  __syncthreads();
  {
    const int c = t & 31, q = t >> 5;
    float a0 = 0.f, a1 = 0.f, a2 = 0.f, a3 = 0.f;
#pragma unroll 8
    for (int m = 0; m < UD; ++m) {
      float4 g4 = *(const float4*)&sGc[m * 36 + 4 * q];
      float km = sKs[m * 33 + c];
      a0 = fmaf(g4.x, km, a0); a1 = fmaf(g4.y, km, a1);
      a2 = fmaf(g4.z, km, a2); a3 = fmaf(g4.w, km, a3);
    }
    const int cc = cb2 + c;
    int r = rb2 + 4 * q;
    float h0 = Hm[(r+0) * KD + cc], h1 = Hm[(r+1) * KD + cc];
    float h2 = Hm[(r+2) * KD + cc], h3 = Hm[(r+3) * KD + cc];
    V[(r+0) * KD + cc] = h0 - a0 + ((r+0 == cc) ? sQd[4*q+0] : 0.f);
    V[(r+1) * KD + cc] = h1 - a1 + ((r+1 == cc) ? sQd[4*q+1] : 0.f);
    V[(r+2) * KD + cc] = h2 - a2 + ((r+2 == cc) ? sQd[4*q+2] : 0.f);
    V[(r+3) * KD + cc] = h3 - a3 + ((r+3 == cc) ? sQd[4*q+3] : 0.f);
  }
  if (hb == 0) {
    int c = t & 31, part = t >> 5;
    float acc2 = 0.f;
#pragma unroll
    for (int m = part * 8; m < part * 8 + 8; ++m) acc2 = fmaf(sKs[m * 33 + c], sZ[m], acc2);
    sRed[part * 36 + c] = acc2;
    __syncthreads();
    if (t < 32)  {
      float s2 = 0.f;
#pragma unroll
      for (int pt = 0; pt < 8; ++pt) s2 += sRed[pt * 36 + t];
      ws[OFF_v + cb2 + t] = ws[OFF_ATV + cb2 + t] - s2 + ws[OFF_QG + cb2 + t];
    }
  }
}

__global__ __launch_bounds__(256) void k_fin(
    const float* __restrict__ W, const float* __restrict__ bphi,
    float* __restrict__ ws)
{
  const int w = blockIdx.x, t = threadIdx.x;
  const float* K0 = ws + OFF_K0;
  if (w >= 1 && t < 128) {
    int j = t & 63, kk = 2 * (w - 1) + (t >> 6);
    float acc = 0.f;
#pragma unroll 8
    for (int i = 0; i < KD; ++i) acc = fmaf(K0[j * KD + i], W[i * XD + kk], acc);
    ws[OFF_NKT + kk * UD + j] = -acc;
  }
  if (w == 0 && t < UD) {
    float acc = 0.f;
#pragma unroll 8
    for (int i = 0; i < KD; ++i) acc = fmaf(K0[t * KD + i], bphi[i], acc);
    ws[OFF_CV + t] = ws[OFF_KV + t] - acc;
  }
}

__global__ __launch_bounds__(256) void k_batch(const float* __restrict__ x0,
                                               const float* __restrict__ ws,
                                               float* __restrict__ out)
{
  __shared__ float kt[XD][UD];
  __shared__ float cvs[UD];
  const int t = threadIdx.x;
  {
    const float4* src = (const float4*)(ws + OFF_NKT);
    float4* dst = (float4*)kt;
#pragma unroll
    for (int idx = 0; idx < (XD * UD / 4) / 256; ++idx)
      dst[t + idx * 256] = src[t + idx * 256];
  }
  if (t < UD) cvs[t] = ws[OFF_CV + t];
  __syncthreads();

  const int ty = t >> 4, tx = t & 15;
  const long r0 = (long)blockIdx.x * 64 + ty * 4;
  const float* xp = x0 + r0 * XD;

#define FMA4(acc, s, f4)                      \
  acc.x = fmaf((s), (f4).x, acc.x);           \
  acc.y = fmaf((s), (f4).y, acc.y);           \
  acc.z = fmaf((s), (f4).z, acc.z);           \
  acc.w = fmaf((s), (f4).w, acc.w);

  float4 acc0 = {0,0,0,0}, acc1 = {0,0,0,0}, acc2 = {0,0,0,0}, acc3 = {0,0,0,0};
#pragma unroll 2
  for (int k = 0; k < XD; k += 4) {
    float4 x_0 = *(const float4*)(xp + 0 * XD + k);
    float4 x_1 = *(const float4*)(xp + 1 * XD + k);
    float4 x_2 = *(const float4*)(xp + 2 * XD + k);
    float4 x_3 = *(const float4*)(xp + 3 * XD + k);
    float4 k_0 = *(const float4*)&kt[k + 0][tx * 4];
    float4 k_1 = *(const float4*)&kt[k + 1][tx * 4];
    float4 k_2 = *(const float4*)&kt[k + 2][tx * 4];
    float4 k_3 = *(const float4*)&kt[k + 3][tx * 4];
    FMA4(acc0, x_0.x, k_0) FMA4(acc0, x_0.y, k_1) FMA4(acc0, x_0.z, k_2) FMA4(acc0, x_0.w, k_3)
    FMA4(acc1, x_1.x, k_0) FMA4(acc1, x_1.y, k_1) FMA4(acc1, x_1.z, k_2) FMA4(acc1, x_1.w, k_3)
    FMA4(acc2, x_2.x, k_0) FMA4(acc2, x_2.y, k_1) FMA4(acc2, x_2.z, k_2) FMA4(acc2, x_2.w, k_3)
    FMA4(acc3, x_3.x, k_0) FMA4(acc3, x_3.y, k_1) FMA4(acc3, x_3.z, k_2) FMA4(acc3, x_3.w, k_3)
  }
  float4 cq = *(float4*)&cvs[tx * 4];
  acc0.x += cq.x; acc0.y += cq.y; acc0.z += cq.z; acc0.w += cq.w;
  acc1.x += cq.x; acc1.y += cq.y; acc1.z += cq.z; acc1.w += cq.w;
  acc2.x += cq.x; acc2.y += cq.y; acc2.z += cq.z; acc2.w += cq.w;
  acc3.x += cq.x; acc3.y += cq.y; acc3.z += cq.z; acc3.w += cq.w;
  *(float4*)(out + (r0 + 0) * UD + tx * 4) = acc0;
  *(float4*)(out + (r0 + 1) * UD + tx * 4) = acc1;
  *(float4*)(out + (r0 + 2) * UD + tx * 4) = acc2;
  *(float4*)(out + (r0 + 3) * UD + tx * 4) = acc3;
}

extern "C" void kernel_launch(void* const* d_in, const int* in_sizes, int n_in,
                              void* d_out, int out_size, void* d_ws, size_t ws_size,
                              hipStream_t stream) {
  const float* x0   = (const float*)d_in[0];
  const float* Wp   = (const float*)d_in[1];
  const float* bphi = (const float*)d_in[2];
  const float* xg   = (const float*)d_in[3];
  const float* A    = (const float*)d_in[4];
  const float* B    = (const float*)d_in[5];
  const float* ql   = (const float*)d_in[6];
  const float* rl   = (const float*)d_in[7];
  float* ws  = (float*)d_ws;
  float* out = (float*)d_out;

  double* base = (double*)d_ws + DBASE;
  double* Em[3] = { base + 0*DBUF, base + 3*DBUF, base + 6*DBUF };
  double* Gm[3] = { base + 1*DBUF, base + 4*DBUF, base + 7*DBUF };
  double* Hm[3] = { base + 2*DBUF, base + 5*DBUF, base + 8*DBUF };
  double* Wb  = base + 9*DBUF;
  double* Pb  = base + 10*DBUF;
  double* T1b = base + 11*DBUF;
  double* T2b = base + 12*DBUF;
  double* X3b = base + 13*DBUF;    // also ping-pong scratch for k_pinv
  double* MB  = base + 14*DBUF;
  double* B64 = MB;
  double* Bs64= MB + 16384;
  double* ev[3] = { MB + 32768, MB + 33280, MB + 33792 };
  double* hv[3] = { MB + 33024, MB + 33536, MB + 34048 };
  double* q1  = MB + 34304;
  double* w12 = MB + 34560;
  double* u1  = MB + 34816;
  double* u2  = MB + 35072;
  double* t5  = MB + 35328;

  GJ gz{}; VJ vz{};

  hipLaunchKernelGGL(k_init, dim3(5), dim3(256), 0, stream, Wp, bphi, xg, ql, rl, ws);
  hipLaunchKernelGGL(k_cvt, dim3(256), dim3(256), 0, stream, A, B, ws);
  // G1 = S = Bs @ B^T
  {
    GJ g0{ Bs64, B64, nullptr, Gm[0], 64, 1, 1, 64, 64, 0 };
    hipLaunchKernelGGL(k_gemm64, dim3(64), dim3(256), 0, stream, g0, gz, gz, 1, vz, vz, vz);
  }

  auto comp = [&](int ia, int ib, int io) {
    double *Ea = Em[ia], *Ga = Gm[ia], *Ha = Hm[ia], *ea = ev[ia], *ha = hv[ia];
    double *Eb = Em[ib], *Gb = Gm[ib], *Hb = Hm[ib], *eb = ev[ib], *hb = hv[ib];
    double *Eo = Em[io], *Go = Gm[io], *Ho = Hm[io], *eo = ev[io], *ho = hv[io];
    // L1: Y = I + Ga@Hb -> Wb ; q1 = Ga@hb
    {
      GJ g0{ Ga, Hb, nullptr, Wb, 256, 1, 256, 1, 256, 1 };
      VJ v0{ Ga, hb, nullptr, q1, 256, 1, 1.0 };
      hipLaunchKernelGGL(k_gemm64, dim3(65), dim3(256), 0, stream, g0, gz, gz, 1, v0, vz, vz);
    }
    // L2: Wb = inv(Wb) via 4 multi-WG panel launches (ping-pong Wb <-> X3b)
    hipLaunchKernelGGL(k_pinv, dim3(64), dim3(256), 0, stream, Wb,  X3b, 0);
    hipLaunchKernelGGL(k_pinv, dim3(64), dim3(256), 0, stream, X3b, Wb,  1);
    hipLaunchKernelGGL(k_pinv, dim3(64), dim3(256), 0, stream, Wb,  X3b, 2);
    hipLaunchKernelGGL(k_pinv, dim3(64), dim3(256), 0, stream, X3b, Wb,  3);
    // L3: P = W@Ea ; T1 = W@Ga ; w12 = -W@q1 ; u1 = W@ea
    {
      GJ g0{ Wb, Ea, nullptr, Pb, 256, 1, 256, 1, 256, 0 };
      GJ g1{ Wb, Ga, nullptr, T1b, 256, 1, 256, 1, 256, 0 };
      VJ v0{ Wb, q1, nullptr, w12, 256, 1, -1.0 };
      VJ v1{ Wb, ea, nullptr, u1, 256, 1, 1.0 };
      hipLaunchKernelGGL(k_gemm64, dim3(130), dim3(256), 0, stream, g0, g1, gz, 2, v0, v1, vz);
    }
    // L4: Eo = Eb@P ; T2 = Eb@T1 ; X3 = Hb@P ; eo = Eb@w12+eb ; u2 = Hb@u1 ; t5 = P^T@hb+ha
    {
      GJ g0{ Eb, Pb, nullptr, Eo, 256, 1, 256, 1, 256, 0 };
      GJ g1{ Eb, T1b, nullptr, T2b, 256, 1, 256, 1, 256, 0 };
      GJ g2{ Hb, Pb, nullptr, X3b, 256, 1, 256, 1, 256, 0 };
      VJ v0{ Eb, w12, eb, eo, 256, 1, 1.0 };
      VJ v1{ Hb, u1, nullptr, u2, 256, 1, 1.0 };
      VJ v2{ Pb, hb, ha, t5, 1, 256, 1.0 };
      hipLaunchKernelGGL(k_gemm64, dim3(195), dim3(256), 0, stream, g0, g1, g2, 3, v0, v1, v2);
    }
    // L5: Go = Gb + T2@Eb^T ; Ho = Ha + Ea^T@X3 ; ho = Ea^T@u2 + t5
    {
      GJ g0{ T2b, Eb, Gb, Go, 256, 1, 1, 256, 256, 0 };
      GJ g1{ Ea, X3b, Ha, Ho, 1, 256, 256, 1, 256, 0 };
      VJ v0{ Ea, u2, t5, ho, 1, 256, 1.0 };
      hipLaunchKernelGGL(k_gemm64, dim3(129), dim3(256), 0, stream, g0, g1, gz, 2, v0, vz, vz);
    }
  };

  // T2 -> T4 -> T8 -> T16 -> T32 -> T64 -> T72 -> T128 -> T200
  comp(0, 0, 1);   // T2
  comp(1, 1, 0);   // T4
  comp(0, 0, 1);   // T8
  comp(1, 1, 2);   // T16
  comp(2, 2, 0);   // T32
  comp(0, 0, 2);   // T64
  comp(2, 1, 0);   // T72  = T64 o T8
  comp(2, 2, 1);   // T128 = T64 o T64
  comp(1, 0, 2);   // T200 = T128 o T72

  // V_199 = H(T200), v_199 = -h(T200); then the 200th scan call (verified kernels)
  hipLaunchKernelGGL(k_fin2, dim3(256), dim3(256), 0, stream, ws);
  hipLaunchKernelGGL(k_ph1, dim3(64), dim3(256), 0, stream, A, B, ws);
  hipLaunchKernelGGL(k_ph2, dim3(65), dim3(256), 0, stream, A, B, ws, 1);
  hipLaunchKernelGGL(k_ph3, dim3(64), dim3(256), 0, stream, ws, 1);
  hipLaunchKernelGGL(k_fin, dim3(65), dim3(256), 0, stream, Wp, bphi, ws);
  int rows = in_sizes[0] / XD;
  int nblk = rows / 64;
  hipLaunchKernelGGL(k_batch, dim3(nblk), dim3(256), 0, stream, x0, ws, out);
}

// Round 11
// 2479.499 us; speedup vs baseline: 7.0568x; 1.0277x over previous
//
#include <hip/hip_runtime.h>
#include <math.h>

#define KD 256
#define UD 64
#define XD 128

// ws float offsets (single-step machinery, unchanged from R6)
#define OFF_V     0
#define OFF_WA    65536
#define OFF_H     131072
#define OFF_G     196608
#define OFF_K0    212992
#define OFF_MI    229376
#define OFF_MP    233472
#define OFF_v     266240
#define OFF_ATV   266496
#define OFF_Z     266752
#define OFF_QG    266816
#define OFF_QD    267072
#define OFF_RD    267328
#define OFF_KV    267392
#define OFF_CV    267456
#define OFF_NKT   267520
// SDA fp64 buffers start at float index 278528 (= double index 139264)
#define DBASE     139264
#define DBUF      65536

__device__ __forceinline__ void inv4(float* D) {
#pragma unroll
  for (int p = 0; p < 4; ++p) {
    float ip = 1.0f / D[p * 4 + p];
#pragma unroll
    for (int i2 = 0; i2 < 4; ++i2)
      if (i2 != p) {
        float f = D[i2 * 4 + p] * ip;
#pragma unroll
        for (int j = 0; j < 4; ++j)
          if (j != p) D[i2 * 4 + j] -= f * D[p * 4 + j];
        D[i2 * 4 + p] = -f;
      }
#pragma unroll
    for (int j = 0; j < 4; ++j)
      if (j != p) D[p * 4 + j] *= ip;
    D[p * 4 + p] = ip;
  }
}

__device__ __forceinline__ void inv4d(double* D) {
#pragma unroll
  for (int p = 0; p < 4; ++p) {
    double ip = 1.0 / D[p * 4 + p];
#pragma unroll
    for (int i2 = 0; i2 < 4; ++i2)
      if (i2 != p) {
        double f = D[i2 * 4 + p] * ip;
#pragma unroll
        for (int j = 0; j < 4; ++j)
          if (j != p) D[i2 * 4 + j] -= f * D[p * 4 + j];
        D[i2 * 4 + p] = -f;
      }
#pragma unroll
    for (int j = 0; j < 4; ++j)
      if (j != p) D[p * 4 + j] *= ip;
    D[p * 4 + p] = ip;
  }
}

#define R16(OP) OP(0) OP(1) OP(2) OP(3) OP(4) OP(5) OP(6) OP(7) OP(8) OP(9) OP(10) OP(11) OP(12) OP(13) OP(14) OP(15)

// ================= seed: init + fp64 seeds + S = Bs@B^T, one launch =================
__global__ __launch_bounds__(256) void k_seed(
    const float* __restrict__ A, const float* __restrict__ B,
    const float* __restrict__ W, const float* __restrict__ bphi,
    const float* __restrict__ xg, const float* __restrict__ qlog,
    const float* __restrict__ rlog, float* __restrict__ ws)
{
  __shared__ double sird[64];     // 1/exp(rlog)
  double* base = (double*)ws + DBASE;
  double* E1 = base + 0 * DBUF;
  double* S  = base + 1 * DBUF;
  double* H1 = base + 2 * DBUF;
  double* MB = base + 14 * DBUF;
  double* B64 = MB;
  double* Bs64 = MB + 16384;
  double* eA = MB + 32768;
  double* hA = MB + 33024;
  const int t = threadIdx.x;
  if (t < 64) sird[t] = 1.0 / exp((double)rlog[t]);
  __syncthreads();
  const int id = blockIdx.x * 256 + t;     // 0..65535
  const int i = id >> 8, j = id & 255;
  E1[id] = (double)A[id];
  H1[id] = (i == j) ? (double)expf(qlog[i]) : 0.0;
  {
    const float* Bi = B + i * 64;
    const float* Bj = B + j * 64;
    double acc = 0.0;
#pragma unroll 8
    for (int m = 0; m < 64; ++m)
      acc = fma((double)Bi[m] * sird[m], (double)Bj[m], acc);
    S[id] = acc;
  }
  if (id < 16384) {
    B64[id] = (double)B[id];
    Bs64[id] = (double)B[id] * sird[id & 63];
  }
  if (id < 256) {
    float acc = 0.f;
    for (int p = 0; p < XD; ++p) acc = fmaf(W[id * XD + p], xg[p], acc);
    float g = acc + bphi[id];
    float qd = expf(qlog[id]);
    ws[OFF_QD + id] = qd; ws[OFF_QG + id] = qd * g;
    eA[id] = 0.0;
    hA[id] = -(double)(qd * g);
  }
  if (id < 64) ws[OFF_RD + id] = expf(rlog[id]);
}

// ================= fp64 batched GEMM/matvec job kernel =================
struct GJ { const double* A; const double* B; const double* C; double* O;
            int sA0, sA1, sB0, sB1, K, addI; };
struct VJ { const double* M1; const double* x; const double* a; double* o;
            int s0, s1; double sgn;
            const double* M2; const double* x2; int s20, s21; double sgn2; };

__global__ __launch_bounds__(256) void k_gemm64(GJ g0, GJ g1, GJ g2, int ng,
                                                VJ v0, VJ v1, VJ v2)
{
  __shared__ double As[32 * 33];
  __shared__ double Bs[32 * 33];
  __shared__ double xs[256];
  __shared__ double xs2[256];
  const int wg = blockIdx.x, t = threadIdx.x;
  if (wg < ng * 64) {
    GJ j = (wg < 64) ? g0 : (wg < 128) ? g1 : g2;
    const int w2 = wg & 63;
    const int tm0 = (w2 >> 3) * 32, tn0 = (w2 & 7) * 32;
    const int rq = t >> 5, c = t & 31;
    double a0 = 0, a1 = 0, a2 = 0, a3 = 0;
    for (int k0 = 0; k0 < j.K; k0 += 32) {
#pragma unroll
      for (int q = 0; q < 4; ++q) {
        int lin = q * 256 + t; int r = lin >> 5, kk = lin & 31;
        As[r * 33 + kk] = j.A[(long)(tm0 + r) * j.sA0 + (long)(k0 + kk) * j.sA1];
        Bs[r * 33 + kk] = j.B[(long)(k0 + r) * j.sB0 + (long)(tn0 + kk) * j.sB1];
      }
      __syncthreads();
#pragma unroll 8
      for (int kk = 0; kk < 32; ++kk) {
        double b = Bs[kk * 33 + c];
        a0 = fma(As[(rq * 4 + 0) * 33 + kk], b, a0);
        a1 = fma(As[(rq * 4 + 1) * 33 + kk], b, a1);
        a2 = fma(As[(rq * 4 + 2) * 33 + kk], b, a2);
        a3 = fma(As[(rq * 4 + 3) * 33 + kk], b, a3);
      }
      __syncthreads();
    }
    const int n = tn0 + c;
    double av[4] = {a0, a1, a2, a3};
#pragma unroll
    for (int i2 = 0; i2 < 4; ++i2) {
      int m = tm0 + rq * 4 + i2;
      double v = av[i2];
      if (j.C) v += j.C[m * 256 + n];
      if (j.addI && m == n) v += 1.0;
      j.O[m * 256 + n] = v;
    }
  } else {
    const int vi = wg - ng * 64;
    VJ j = (vi == 0) ? v0 : (vi == 1) ? v1 : v2;
    xs[t] = j.x[t];
    if (j.M2) xs2[t] = j.x2[t];
    __syncthreads();
    double acc = 0;
#pragma unroll 8
    for (int k2 = 0; k2 < 256; ++k2)
      acc = fma(j.M1[(long)t * j.s0 + (long)k2 * j.s1], xs[k2], acc);
    double o = j.sgn * acc;
    if (j.M2) {
      double acc2 = 0;
#pragma unroll 8
      for (int k2 = 0; k2 < 256; ++k2)
        acc2 = fma(j.M2[(long)t * j.s20 + (long)k2 * j.s21], xs2[k2], acc2);
      o += j.sgn2 * acc2;
    }
    if (j.a) o += j.a[t];
    j.o[t] = o;
  }
}

// ================= fp64 256x256 inverse: one PANEL step (64 WGs, ping-pong) ====
// Verified in R10. Blocked unpivoted Gauss-Jordan, panel width 64, 4 launches.
__global__ __launch_bounds__(256) void k_pinv(const double* __restrict__ Yc,
                                              double* __restrict__ Yn, int pk)
{
  const int w = blockIdx.x, t = threadIdx.x;
  const int bi = w >> 3, bj = w & 7;       // 32-wide tile block coords
  const int p0 = pk * 64, pb = pk * 2;     // panel col start / block index
  const int r0 = bi * 32, c0 = bj * 32;

  __shared__ double sDI[64 * 65];
  __shared__ double sC [32 * 66];
  __shared__ double sR [64 * 34];
  __shared__ double sL [32 * 66];
  __shared__ double sU [64 * 34];
  __shared__ double sPR[4 * 68];
  __shared__ double sF [64 * 5];

  for (int q = 0; q < 8; ++q) { int lin = q * 256 + t; int r = lin >> 6, m = lin & 63; sC[r * 66 + m] = Yc[(r0 + r) * 256 + p0 + m]; }
  for (int q = 0; q < 8; ++q) { int lin = q * 256 + t; int m = lin >> 5, c = lin & 31; sR[m * 34 + c] = Yc[(p0 + m) * 256 + c0 + c]; }

  // fp64 rank-4 GJ inverse of D (redundant per WG)
  const int i = t & 63, cg = t >> 6;
  double rr[16];
#pragma unroll
  for (int q = 0; q < 16; ++q) rr[q] = Yc[(p0 + i) * 256 + p0 + cg * 16 + q];
  for (int k = 0; k < 16; ++k) {
    const int prw = i - 4 * k;
    const bool inblk = (unsigned)prw < 4u;
    if (inblk) {
#pragma unroll
      for (int q = 0; q < 16; ++q) sPR[prw * 68 + cg * 16 + q] = rr[q];
    }
    if (cg == (k >> 2)) {
      const int b = (k & 3) * 4;
      sF[i * 5 + 0] = rr[b + 0]; sF[i * 5 + 1] = rr[b + 1];
      sF[i * 5 + 2] = rr[b + 2]; sF[i * 5 + 3] = rr[b + 3];
    }
    __syncthreads();
    double D[16];
#pragma unroll
    for (int q = 0; q < 4; ++q) {
      D[q * 4 + 0] = sPR[q * 68 + 4 * k + 0];
      D[q * 4 + 1] = sPR[q * 68 + 4 * k + 1];
      D[q * 4 + 2] = sPR[q * 68 + 4 * k + 2];
      D[q * 4 + 3] = sPR[q * 68 + 4 * k + 3];
    }
    inv4d(D);
    double f0 = sF[i * 5 + 0], f1 = sF[i * 5 + 1], f2 = sF[i * 5 + 2], f3 = sF[i * 5 + 3];
    double g0, g1, g2, g3;
    if (inblk) {
      g0 = prw == 0 ? D[0] : prw == 1 ? D[4] : prw == 2 ? D[8]  : D[12];
      g1 = prw == 0 ? D[1] : prw == 1 ? D[5] : prw == 2 ? D[9]  : D[13];
      g2 = prw == 0 ? D[2] : prw == 1 ? D[6] : prw == 2 ? D[10] : D[14];
      g3 = prw == 0 ? D[3] : prw == 1 ? D[7] : prw == 2 ? D[11] : D[15];
    } else {
      g0 = f0 * D[0] + f1 * D[4] + f2 * D[8]  + f3 * D[12];
      g1 = f0 * D[1] + f1 * D[5] + f2 * D[9]  + f3 * D[13];
      g2 = f0 * D[2] + f1 * D[6] + f2 * D[10] + f3 * D[14];
      g3 = f0 * D[3] + f1 * D[7] + f2 * D[11] + f3 * D[15];
    }
#pragma unroll
    for (int q = 0; q < 16; ++q) {
      double pr0 = sPR[0 * 68 + cg * 16 + q];
      double pr1 = sPR[1 * 68 + cg * 16 + q];
      double pr2 = sPR[2 * 68 + cg * 16 + q];
      double pr3 = sPR[3 * 68 + cg * 16 + q];
      double n = fma(g0, pr0, fma(g1, pr1, fma(g2, pr2, g3 * pr3)));
      rr[q] = inblk ? n : rr[q] - n;
    }
    if (cg == (k >> 2)) {
      const int b = (k & 3) * 4;
      rr[b + 0] = inblk ? g0 : -g0; rr[b + 1] = inblk ? g1 : -g1;
      rr[b + 2] = inblk ? g2 : -g2; rr[b + 3] = inblk ? g3 : -g3;
    }
    __syncthreads();
  }
#pragma unroll
  for (int q = 0; q < 16; ++q) sDI[i * 65 + cg * 16 + q] = rr[q];
  __syncthreads();

  // L = sC @ sDI (32x64), U = sDI @ sR (64x32)
  {
    const int r = t >> 3, u0 = (t & 7) * 8;
    double acc[8];
#pragma unroll
    for (int u = 0; u < 8; ++u) acc[u] = 0.0;
#pragma unroll 4
    for (int m = 0; m < 64; ++m) {
      double cv = sC[r * 66 + m];
#pragma unroll
      for (int u = 0; u < 8; ++u) acc[u] = fma(cv, sDI[m * 65 + u0 + u], acc[u]);
    }
#pragma unroll
    for (int u = 0; u < 8; ++u) sL[r * 66 + u0 + u] = acc[u];
  }
  {
    const int qrow = t >> 2, c4 = (t & 3) * 8;
    double acc[8];
#pragma unroll
    for (int u = 0; u < 8; ++u) acc[u] = 0.0;
#pragma unroll 4
    for (int m = 0; m < 64; ++m) {
      double dv = sDI[qrow * 65 + m];
#pragma unroll
      for (int u = 0; u < 8; ++u) acc[u] = fma(dv, sR[m * 34 + c4 + u], acc[u]);
    }
#pragma unroll
    for (int u = 0; u < 8; ++u) sU[qrow * 34 + c4 + u] = acc[u];
  }
  __syncthreads();

  const bool rip = (bi == pb || bi == pb + 1);
  const bool cip = (bj == pb || bj == pb + 1);
  const int r = t >> 3, cc4 = (t & 7) * 4;
#pragma unroll
  for (int u = 0; u < 4; ++u) {
    const int c = cc4 + u;
    double outv;
    if (rip && cip) {
      outv = sDI[((bi - pb) * 32 + r) * 65 + (bj - pb) * 32 + c];
    } else if (cip) {
      outv = -sL[r * 66 + (bj - pb) * 32 + c];
    } else if (rip) {
      outv = sU[((bi - pb) * 32 + r) * 34 + c];
    } else {
      double acc = Yc[(r0 + r) * 256 + c0 + c];
#pragma unroll 8
      for (int q = 0; q < 64; ++q) acc = fma(-sC[r * 66 + q], sU[q * 34 + c], acc);
      outv = acc;
    }
    Yn[(r0 + r) * 256 + c0 + c] = outv;
  }
}

// ================= fin2: V = (float)H_final, vv = -(float)h_final =================
__global__ __launch_bounds__(256) void k_fin2(float* __restrict__ ws)
{
  double* base = (double*)ws + DBASE;
  double* Hf = base + 8 * DBUF;              // Hm[2]
  double* hf = base + 14 * DBUF + 34048;     // hv[2]
  int id = blockIdx.x * 256 + threadIdx.x;
  ws[OFF_V + id] = (float)Hf[id];
  if (id < 256) ws[OFF_v + id] = -(float)hf[id];
}

// ================= single Riccati step (verified R6 kernels, unchanged) =================
__global__ __launch_bounds__(256) void k_ph1(
    const float* __restrict__ A, const float* __restrict__ B,
    float* __restrict__ ws)
{
  const int u = blockIdx.x, t = threadIdx.x;
  const int sb = u & 7, hb = u >> 3;
  const int rb = sb * 32, cb0 = hb * 32, m0 = hb * 8;
  float* V   = ws + OFF_V;
  float* WAg = ws + OFF_WA;

  __shared__ float sVt[256 * 36];
  __shared__ float sA [256 * 36];
  __shared__ float sBsl[256 * 8];
  __shared__ float sBr[32 * 64];
  __shared__ float svv[256];
  __shared__ float sVB[32 * 9];
  __shared__ float sRed[8 * 36];

  for (int q = 0; q < 8; ++q) {
    int idx = q * 256 + t; int p = idx >> 3, r4 = (idx & 7) * 4;
    *(float4*)&sVt[p * 36 + r4] = *(const float4*)(V + p * KD + rb + r4);
  }
  for (int q = 0; q < 8; ++q) {
    int idx = q * 256 + t; int p = idx >> 3, r4 = (idx & 7) * 4;
    *(float4*)&sA[p * 36 + r4] = *(const float4*)(A + p * KD + cb0 + r4);
  }
  for (int q = 0; q < 2; ++q) {
    int idx = q * 256 + t; int p = idx >> 1, j4 = (idx & 1) * 4;
    *(float4*)&sBsl[p * 8 + j4] = *(const float4*)(B + p * UD + m0 + j4);
  }
  for (int q = 0; q < 2; ++q) {
    int idx = q * 256 + t; int r = idx >> 4, a4 = (idx & 15) * 4;
    *(float4*)&sBr[r * 64 + a4] = *(const float4*)(B + (rb + r) * UD + a4);
  }
  svv[t] = ws[OFF_v + t];
  __syncthreads();

  const int j = t & 31, rq = t >> 5;
  float4 acc = {0.f, 0.f, 0.f, 0.f};
  float avb0 = 0.f, avb1 = 0.f, avb2 = 0.f, avb3 = 0.f;
  const bool dovb = (j < 8);
#pragma unroll 8
  for (int p = 0; p < KD; ++p) {
    float4 v4 = *(const float4*)&sVt[p * 36 + rq * 4];
    float a = sA[p * 36 + j];
    acc.x = fmaf(v4.x, a, acc.x);
    acc.y = fmaf(v4.y, a, acc.y);
    acc.z = fmaf(v4.z, a, acc.z);
    acc.w = fmaf(v4.w, a, acc.w);
    if (dovb) {
      float b = sBsl[p * 8 + j];
      avb0 = fmaf(v4.x, b, avb0);
      avb1 = fmaf(v4.y, b, avb1);
      avb2 = fmaf(v4.z, b, avb2);
      avb3 = fmaf(v4.w, b, avb3);
    }
  }
  WAg[(rb + 4 * rq + 0) * KD + cb0 + j] = acc.x;
  WAg[(rb + 4 * rq + 1) * KD + cb0 + j] = acc.y;
  WAg[(rb + 4 * rq + 2) * KD + cb0 + j] = acc.z;
  WAg[(rb + 4 * rq + 3) * KD + cb0 + j] = acc.w;
  if (dovb) {
    sVB[(4 * rq + 0) * 9 + j] = avb0;
    sVB[(4 * rq + 1) * 9 + j] = avb1;
    sVB[(4 * rq + 2) * 9 + j] = avb2;
    sVB[(4 * rq + 3) * 9 + j] = avb3;
  }
  if (sb == 0) {
    int c = t & 31, part = t >> 5;
    float acc2 = 0.f;
#pragma unroll 8
    for (int p = part * 32; p < part * 32 + 32; ++p) acc2 = fmaf(sA[p * 36 + c], svv[p], acc2);
    sRed[part * 36 + c] = acc2;
  }
  if (sb == 1 && t < 64) {
    int jz = t & 7, part = t >> 3;
    float acc2 = 0.f;
#pragma unroll 8
    for (int p = part * 32; p < part * 32 + 32; ++p) acc2 = fmaf(sBsl[p * 8 + jz], svv[p], acc2);
    sRed[part * 36 + jz] = acc2;
  }
  __syncthreads();
  {
    int a = t & 63, j2 = (t >> 6) * 2;
    float mp0 = 0.f, mp1 = 0.f;
#pragma unroll 8
    for (int r = 0; r < 32; ++r) {
      float bv = sBr[r * 64 + a];
      mp0 = fmaf(bv, sVB[r * 9 + j2 + 0], mp0);
      mp1 = fmaf(bv, sVB[r * 9 + j2 + 1], mp1);
    }
    ws[OFF_MP + sb * 4096 + a * 64 + m0 + j2 + 0] = mp0;
    ws[OFF_MP + sb * 4096 + a * 64 + m0 + j2 + 1] = mp1;
  }
  if (sb == 0 && t < 32) {
    float a2 = 0.f;
#pragma unroll
    for (int pt = 0; pt < 8; ++pt) a2 += sRed[pt * 36 + t];
    ws[OFF_ATV + cb0 + t] = a2;
  }
  if (sb == 1 && t < 8) {
    float a2 = 0.f;
#pragma unroll
    for (int pt = 0; pt < 8; ++pt) a2 += sRed[pt * 36 + t];
    ws[OFF_Z + m0 + t] = a2;
  }
}

__global__ __launch_bounds__(256) void k_ph2(
    const float* __restrict__ A, const float* __restrict__ B,
    float* __restrict__ ws, int last)
{
  const int w = blockIdx.x, t = threadIdx.x;
  const int u = w - 1;
  float* WAg = ws + OFF_WA;
  float* MI  = ws + OFF_MI;

  __shared__ float sWA[256 * 33];
  __shared__ float sA [256 * 36];
  __shared__ float sBsl[256 * 8];
  __shared__ float scr[608];
  __shared__ float wred[256];

  if (w == 0) {
    float* sPR = scr;
    float* sF  = scr + 280;
    const int i = t & 63, cg = t >> 6;
    const float rdi = ws[OFF_RD + i];
    float rr[16];
    {
      float4 s0 = {0,0,0,0}, s1 = {0,0,0,0}, s2 = {0,0,0,0}, s3 = {0,0,0,0};
#pragma unroll
      for (int sb2 = 0; sb2 < 8; ++sb2) {
        const float* mp = ws + OFF_MP + sb2 * 4096 + i * 64 + cg * 16;
        float4 a0 = *(const float4*)(mp + 0);
        float4 a1 = *(const float4*)(mp + 4);
        float4 a2 = *(const float4*)(mp + 8);
        float4 a3 = *(const float4*)(mp + 12);
        s0.x += a0.x; s0.y += a0.y; s0.z += a0.z; s0.w += a0.w;
        s1.x += a1.x; s1.y += a1.y; s1.z += a1.z; s1.w += a1.w;
        s2.x += a2.x; s2.y += a2.y; s2.z += a2.z; s2.w += a2.w;
        s3.x += a3.x; s3.y += a3.y; s3.z += a3.z; s3.w += a3.w;
      }
      rr[0]=s0.x; rr[1]=s0.y; rr[2]=s0.z; rr[3]=s0.w;
      rr[4]=s1.x; rr[5]=s1.y; rr[6]=s1.z; rr[7]=s1.w;
      rr[8]=s2.x; rr[9]=s2.y; rr[10]=s2.z; rr[11]=s2.w;
      rr[12]=s3.x; rr[13]=s3.y; rr[14]=s3.z; rr[15]=s3.w;
#define DIAG(j) rr[j] += (cg * 16 + j == i) ? rdi : 0.f;
      R16(DIAG)
#undef DIAG
    }
    for (int k = 0; k < 16; ++k) {
      const int prw = i - 4 * k;
      const bool inblk = (unsigned)prw < 4u;
      if (inblk) {
#define ST(j) sPR[prw * 68 + cg * 16 + j] = rr[j];
        R16(ST)
#undef ST
      }
      if (cg == (k >> 2)) {
        switch (k & 3) {
          case 0: sF[i*5+0]=rr[0];  sF[i*5+1]=rr[1];  sF[i*5+2]=rr[2];  sF[i*5+3]=rr[3];  break;
          case 1: sF[i*5+0]=rr[4];  sF[i*5+1]=rr[5];  sF[i*5+2]=rr[6];  sF[i*5+3]=rr[7];  break;
          case 2: sF[i*5+0]=rr[8];  sF[i*5+1]=rr[9];  sF[i*5+2]=rr[10]; sF[i*5+3]=rr[11]; break;
          default:sF[i*5+0]=rr[12]; sF[i*5+1]=rr[13]; sF[i*5+2]=rr[14]; sF[i*5+3]=rr[15]; break;
        }
      }
      __syncthreads();
      float D[16];
#pragma unroll
      for (int q = 0; q < 4; ++q) {
        D[q*4+0] = sPR[q*68 + 4*k + 0];
        D[q*4+1] = sPR[q*68 + 4*k + 1];
        D[q*4+2] = sPR[q*68 + 4*k + 2];
        D[q*4+3] = sPR[q*68 + 4*k + 3];
      }
      inv4(D);
      float f0 = sF[i*5+0], f1 = sF[i*5+1], f2 = sF[i*5+2], f3 = sF[i*5+3];
      float g0, g1, g2, g3;
      if (inblk) {
        g0 = prw==0?D[0]:prw==1?D[4]:prw==2?D[8]:D[12];
        g1 = prw==0?D[1]:prw==1?D[5]:prw==2?D[9]:D[13];
        g2 = prw==0?D[2]:prw==1?D[6]:prw==2?D[10]:D[14];
        g3 = prw==0?D[3]:prw==1?D[7]:prw==2?D[11]:D[15];
      } else {
        g0 = f0*D[0] + f1*D[4] + f2*D[8]  + f3*D[12];
        g1 = f0*D[1] + f1*D[5] + f2*D[9]  + f3*D[13];
        g2 = f0*D[2] + f1*D[6] + f2*D[10] + f3*D[14];
        g3 = f0*D[3] + f1*D[7] + f2*D[11] + f3*D[15];
      }
#define CHUNK(c4)                                                         \
      {                                                                   \
        float4 p0 = *(const float4*)&sPR[0 * 68 + cg * 16 + (c4) * 4];    \
        float4 p1 = *(const float4*)&sPR[1 * 68 + cg * 16 + (c4) * 4];    \
        float4 p2 = *(const float4*)&sPR[2 * 68 + cg * 16 + (c4) * 4];    \
        float4 p3 = *(const float4*)&sPR[3 * 68 + cg * 16 + (c4) * 4];    \
        float n0 = fmaf(g0,p0.x, fmaf(g1,p1.x, fmaf(g2,p2.x, g3*p3.x)));  \
        float n1 = fmaf(g0,p0.y, fmaf(g1,p1.y, fmaf(g2,p2.y, g3*p3.y)));  \
        float n2 = fmaf(g0,p0.z, fmaf(g1,p1.z, fmaf(g2,p2.z, g3*p3.z)));  \
        float n3 = fmaf(g0,p0.w, fmaf(g1,p1.w, fmaf(g2,p2.w, g3*p3.w)));  \
        if (inblk) { rr[(c4)*4+0]=n0; rr[(c4)*4+1]=n1; rr[(c4)*4+2]=n2; rr[(c4)*4+3]=n3; } \
        else { rr[(c4)*4+0]-=n0; rr[(c4)*4+1]-=n1; rr[(c4)*4+2]-=n2; rr[(c4)*4+3]-=n3; }   \
      }
      CHUNK(0) CHUNK(1) CHUNK(2) CHUNK(3)
#undef CHUNK
      if (cg == (k >> 2)) {
        switch (k & 3) {
          case 0: rr[0] = inblk? g0:-g0; rr[1] = inblk? g1:-g1; rr[2] = inblk? g2:-g2; rr[3] = inblk? g3:-g3; break;
          case 1: rr[4] = inblk? g0:-g0; rr[5] = inblk? g1:-g1; rr[6] = inblk? g2:-g2; rr[7] = inblk? g3:-g3; break;
          case 2: rr[8] = inblk? g0:-g0; rr[9] = inblk? g1:-g1; rr[10]= inblk? g2:-g2; rr[11]= inblk? g3:-g3; break;
          default:rr[12]= inblk? g0:-g0; rr[13]= inblk? g1:-g1; rr[14]= inblk? g2:-g2; rr[15]= inblk? g3:-g3; break;
        }
      }
      __syncthreads();
    }
    *(float4*)(MI + i * 64 + cg * 16 + 0)  = *(float4*)&rr[0];
    *(float4*)(MI + i * 64 + cg * 16 + 4)  = *(float4*)&rr[4];
    *(float4*)(MI + i * 64 + cg * 16 + 8)  = *(float4*)&rr[8];
    *(float4*)(MI + i * 64 + cg * 16 + 12) = *(float4*)&rr[12];
    if (last) {
      float p2 = 0.f;
#define KV(j) p2 = fmaf(rr[j], ws[OFF_Z + cg * 16 + j], p2);
      R16(KV)
#undef KV
      wred[i * 4 + cg] = p2;
      __syncthreads();
      if (t < 64) ws[OFF_KV + t] = wred[t*4+0] + wred[t*4+1] + wred[t*4+2] + wred[t*4+3];
    }
  } else {
    const int sb = u & 7, hb = u >> 3;
    const int rb = sb * 32, cb0 = hb * 32, m0 = hb * 8;
    for (int q = 0; q < 8; ++q) {
      int idx = q * 256 + t;
      int p = idx >> 3, c4 = (idx & 7) * 4;
      float4 v4 = *(const float4*)(WAg + p * KD + rb + c4);
      sWA[p * 33 + c4 + 0] = v4.x;
      sWA[p * 33 + c4 + 1] = v4.y;
      sWA[p * 33 + c4 + 2] = v4.z;
      sWA[p * 33 + c4 + 3] = v4.w;
    }
    for (int q = 0; q < 8; ++q) {
      int idx = q * 256 + t; int p = idx >> 3, r4 = (idx & 7) * 4;
      *(float4*)&sA[p * 36 + r4] = *(const float4*)(A + p * KD + cb0 + r4);
    }
    for (int q = 0; q < 2; ++q) {
      int idx = q * 256 + t; int p = idx >> 1, j4 = (idx & 1) * 4;
      *(float4*)&sBsl[p * 8 + j4] = *(const float4*)(B + p * UD + m0 + j4);
    }
    __syncthreads();
    const int c = t & 31, q = t >> 5;
    float4 hacc = {0.f, 0.f, 0.f, 0.f};
    float gacc = 0.f;
#pragma unroll 8
    for (int p = 0; p < KD; ++p) {
      float wv = sWA[p * 33 + c];
      float4 a4 = *(const float4*)&sA[p * 36 + 4 * q];
      float bq = sBsl[p * 8 + q];
      hacc.x = fmaf(a4.x, wv, hacc.x);
      hacc.y = fmaf(a4.y, wv, hacc.y);
      hacc.z = fmaf(a4.z, wv, hacc.z);
      hacc.w = fmaf(a4.w, wv, hacc.w);
      gacc = fmaf(bq, wv, gacc);
    }
    float* Hm = ws + OFF_H;
    float* Gm = ws + OFF_G;
    Hm[(cb0 + 4*q + 0) * KD + rb + c] = hacc.x;
    Hm[(cb0 + 4*q + 1) * KD + rb + c] = hacc.y;
    Hm[(cb0 + 4*q + 2) * KD + rb + c] = hacc.z;
    Hm[(cb0 + 4*q + 3) * KD + rb + c] = hacc.w;
    Gm[(m0 + q) * KD + rb + c] = gacc;
  }
}

__global__ __launch_bounds__(256) void k_ph3(float* __restrict__ ws, int last)
{
  const int u = blockIdx.x, t = threadIdx.x;
  const int sb = u & 7, hb = u >> 3;
  const int cb2 = sb * 32, rb2 = hb * 32;
  float* V  = ws + OFF_V;
  float* Hm = ws + OFF_H;
  float* Gm = ws + OFF_G;

  __shared__ float sMI_[64 * 65];
  __shared__ float sGb [64 * 36];
  __shared__ float sGc [64 * 36];
  __shared__ float sKs [64 * 33];
  __shared__ float sZ[64];
  __shared__ float sQd[32];
  __shared__ float sRed[8 * 36];

  for (int q = 0; q < 16; ++q) { int idx = q * 256 + t; int row = idx >> 6, col = idx & 63; sMI_[row * 65 + col] = ws[OFF_MI + idx]; }
  for (int q = 0; q < 2; ++q) {
    int idx = q * 256 + t; int m = idx >> 3, c4 = (idx & 7) * 4;
    float4 g4 = *(const float4*)(Gm + m * KD + cb2 + c4);
    sGb[m * 36 + c4 + 0] = g4.x; sGb[m * 36 + c4 + 1] = g4.y;
    sGb[m * 36 + c4 + 2] = g4.z; sGb[m * 36 + c4 + 3] = g4.w;
  }
  for (int q = 0; q < 2; ++q) {
    int idx = q * 256 + t; int m = idx >> 3, c4 = (idx & 7) * 4;
    float4 g4 = *(const float4*)(Gm + m * KD + rb2 + c4);
    sGc[m * 36 + c4 + 0] = g4.x; sGc[m * 36 + c4 + 1] = g4.y;
    sGc[m * 36 + c4 + 2] = g4.z; sGc[m * 36 + c4 + 3] = g4.w;
  }
  if (t < 64) sZ[t] = ws[OFF_Z + t];
  if (t < 32) sQd[t] = ws[OFF_QD + rb2 + t];
  __syncthreads();
  {
    const int m = t & 63, wv = t >> 6;
    float k0=0,k1=0,k2=0,k3=0,k4=0,k5=0,k6=0,k7=0;
#pragma unroll 4
    for (int p = 0; p < UD; ++p) {
      float mi = sMI_[m * 65 + p];
      float4 ga  = *(const float4*)&sGb[p * 36 + wv * 8 + 0];
      float4 gb2 = *(const float4*)&sGb[p * 36 + wv * 8 + 4];
      k0 = fmaf(mi, ga.x, k0); k1 = fmaf(mi, ga.y, k1);
      k2 = fmaf(mi, ga.z, k2); k3 = fmaf(mi, ga.w, k3);
      k4 = fmaf(mi, gb2.x, k4); k5 = fmaf(mi, gb2.y, k5);
      k6 = fmaf(mi, gb2.z, k6); k7 = fmaf(mi, gb2.w, k7);
    }
    sKs[m * 33 + wv * 8 + 0] = k0; sKs[m * 33 + wv * 8 + 1] = k1;
    sKs[m * 33 + wv * 8 + 2] = k2; sKs[m * 33 + wv * 8 + 3] = k3;
    sKs[m * 33 + wv * 8 + 4] = k4; sKs[m * 33 + wv * 8 + 5] = k5;
    sKs[m * 33 + wv * 8 + 6] = k6; sKs[m * 33 + wv * 8 + 7] = k7;
    if (last && hb == 0) {
      float* K0 = ws + OFF_K0;
      K0[m * KD + cb2 + wv * 8 + 0] = k0; K0[m * KD + cb2 + wv * 8 + 1] = k1;
      K0[m * KD + cb2 + wv * 8 + 2] = k2; K0[m * KD + cb2 + wv * 8 + 3] = k3;
      K0[m * KD + cb2 + wv * 8 + 4] = k4; K0[m * KD + cb2 + wv * 8 + 5] = k5;
      K0[m * KD + cb2 + wv * 8 + 6] = k6; K0[m * KD + cb2 + wv * 8 + 7] = k7;
    }
  }
  __syncthreads();
  {
    const int c = t & 31, q = t >> 5;
    float a0 = 0.f, a1 = 0.f, a2 = 0.f, a3 = 0.f;
#pragma unroll 8
    for (int m = 0; m < UD; ++m) {
      float4 g4 = *(const float4*)&sGc[m * 36 + 4 * q];
      float km = sKs[m * 33 + c];
      a0 = fmaf(g4.x, km, a0); a1 = fmaf(g4.y, km, a1);
      a2 = fmaf(g4.z, km, a2); a3 = fmaf(g4.w, km, a3);
    }
    const int cc = cb2 + c;
    int r = rb2 + 4 * q;
    float h0 = Hm[(r+0) * KD + cc], h1 = Hm[(r+1) * KD + cc];
    float h2 = Hm[(r+2) * KD + cc], h3 = Hm[(r+3) * KD + cc];
    V[(r+0) * KD + cc] = h0 - a0 + ((r+0 == cc) ? sQd[4*q+0] : 0.f);
    V[(r+1) * KD + cc] = h1 - a1 + ((r+1 == cc) ? sQd[4*q+1] : 0.f);
    V[(r+2) * KD + cc] = h2 - a2 + ((r+2 == cc) ? sQd[4*q+2] : 0.f);
    V[(r+3) * KD + cc] = h3 - a3 + ((r+3 == cc) ? sQd[4*q+3] : 0.f);
  }
  if (hb == 0) {
    int c = t & 31, part = t >> 5;
    float acc2 = 0.f;
#pragma unroll
    for (int m = part * 8; m < part * 8 + 8; ++m) acc2 = fmaf(sKs[m * 33 + c], sZ[m], acc2);
    sRed[part * 36 + c] = acc2;
    __syncthreads();
    if (t < 32)  {
      float s2 = 0.f;
#pragma unroll
      for (int pt = 0; pt < 8; ++pt) s2 += sRed[pt * 36 + t];
      ws[OFF_v + cb2 + t] = ws[OFF_ATV + cb2 + t] - s2 + ws[OFF_QG + cb2 + t];
    }
  }
}

__global__ __launch_bounds__(256) void k_fin(
    const float* __restrict__ W, const float* __restrict__ bphi,
    float* __restrict__ ws)
{
  const int w = blockIdx.x, t = threadIdx.x;
  const float* K0 = ws + OFF_K0;
  if (w >= 1 && t < 128) {
    int j = t & 63, kk = 2 * (w - 1) + (t >> 6);
    float acc = 0.f;
#pragma unroll 8
    for (int i = 0; i < KD; ++i) acc = fmaf(K0[j * KD + i], W[i * XD + kk], acc);
    ws[OFF_NKT + kk * UD + j] = -acc;
  }
  if (w == 0 && t < UD) {
    float acc = 0.f;
#pragma unroll 8
    for (int i = 0; i < KD; ++i) acc = fmaf(K0[t * KD + i], bphi[i], acc);
    ws[OFF_CV + t] = ws[OFF_KV + t] - acc;
  }
}

__global__ __launch_bounds__(256) void k_batch(const float* __restrict__ x0,
                                               const float* __restrict__ ws,
                                               float* __restrict__ out)
{
  __shared__ float kt[XD][UD];
  __shared__ float cvs[UD];
  const int t = threadIdx.x;
  {
    const float4* src = (const float4*)(ws + OFF_NKT);
    float4* dst = (float4*)kt;
#pragma unroll
    for (int idx = 0; idx < (XD * UD / 4) / 256; ++idx)
      dst[t + idx * 256] = src[t + idx * 256];
  }
  if (t < UD) cvs[t] = ws[OFF_CV + t];
  __syncthreads();

  const int ty = t >> 4, tx = t & 15;

#define FMA4(acc, s, f4)                      \
  acc.x = fmaf((s), (f4).x, acc.x);           \
  acc.y = fmaf((s), (f4).y, acc.y);           \
  acc.z = fmaf((s), (f4).z, acc.z);           \
  acc.w = fmaf((s), (f4).w, acc.w);

  float4 cq = *(float4*)&cvs[tx * 4];
#pragma unroll
  for (int half = 0; half < 2; ++half) {
    const long r0 = (long)blockIdx.x * 128 + half * 64 + ty * 4;
    const float* xp = x0 + r0 * XD;
    float4 acc0 = {0,0,0,0}, acc1 = {0,0,0,0}, acc2 = {0,0,0,0}, acc3 = {0,0,0,0};
#pragma unroll 2
    for (int k = 0; k < XD; k += 4) {
      float4 x_0 = *(const float4*)(xp + 0 * XD + k);
      float4 x_1 = *(const float4*)(xp + 1 * XD + k);
      float4 x_2 = *(const float4*)(xp + 2 * XD + k);
      float4 x_3 = *(const float4*)(xp + 3 * XD + k);
      float4 k_0 = *(const float4*)&kt[k + 0][tx * 4];
      float4 k_1 = *(const float4*)&kt[k + 1][tx * 4];
      float4 k_2 = *(const float4*)&kt[k + 2][tx * 4];
      float4 k_3 = *(const float4*)&kt[k + 3][tx * 4];
      FMA4(acc0, x_0.x, k_0) FMA4(acc0, x_0.y, k_1) FMA4(acc0, x_0.z, k_2) FMA4(acc0, x_0.w, k_3)
      FMA4(acc1, x_1.x, k_0) FMA4(acc1, x_1.y, k_1) FMA4(acc1, x_1.z, k_2) FMA4(acc1, x_1.w, k_3)
      FMA4(acc2, x_2.x, k_0) FMA4(acc2, x_2.y, k_1) FMA4(acc2, x_2.z, k_2) FMA4(acc2, x_2.w, k_3)
      FMA4(acc3, x_3.x, k_0) FMA4(acc3, x_3.y, k_1) FMA4(acc3, x_3.z, k_2) FMA4(acc3, x_3.w, k_3)
    }
    acc0.x += cq.x; acc0.y += cq.y; acc0.z += cq.z; acc0.w += cq.w;
    acc1.x += cq.x; acc1.y += cq.y; acc1.z += cq.z; acc1.w += cq.w;
    acc2.x += cq.x; acc2.y += cq.y; acc2.z += cq.z; acc2.w += cq.w;
    acc3.x += cq.x; acc3.y += cq.y; acc3.z += cq.z; acc3.w += cq.w;
    *(float4*)(out + (r0 + 0) * UD + tx * 4) = acc0;
    *(float4*)(out + (r0 + 1) * UD + tx * 4) = acc1;
    *(float4*)(out + (r0 + 2) * UD + tx * 4) = acc2;
    *(float4*)(out + (r0 + 3) * UD + tx * 4) = acc3;
  }
}

extern "C" void kernel_launch(void* const* d_in, const int* in_sizes, int n_in,
                              void* d_out, int out_size, void* d_ws, size_t ws_size,
                              hipStream_t stream) {
  const float* x0   = (const float*)d_in[0];
  const float* Wp   = (const float*)d_in[1];
  const float* bphi = (const float*)d_in[2];
  const float* xg   = (const float*)d_in[3];
  const float* A    = (const float*)d_in[4];
  const float* B    = (const float*)d_in[5];
  const float* ql   = (const float*)d_in[6];
  const float* rl   = (const float*)d_in[7];
  float* ws  = (float*)d_ws;
  float* out = (float*)d_out;

  double* base = (double*)d_ws + DBASE;
  double* Em[3] = { base + 0*DBUF, base + 3*DBUF, base + 6*DBUF };
  double* Gm[3] = { base + 1*DBUF, base + 4*DBUF, base + 7*DBUF };
  double* Hm[3] = { base + 2*DBUF, base + 5*DBUF, base + 8*DBUF };
  double* Wb  = base + 9*DBUF;
  double* Pb  = base + 10*DBUF;
  double* T1b = base + 11*DBUF;
  double* Jb  = base + 12*DBUF;    // J = Ea^T @ Hb (was T2b)
  double* X3b = base + 13*DBUF;    // pinv ping-pong scratch
  double* Nb  = (double*)d_ws + 32768;  // N = Ga@Eb^T, aliases fp32 WA/H region (tail-only)
  double* MB  = base + 14*DBUF;
  double* ev[3] = { MB + 32768, MB + 33280, MB + 33792 };
  double* hv[3] = { MB + 33024, MB + 33536, MB + 34048 };
  double* q1  = MB + 34304;
  double* w12 = MB + 34560;
  double* u1  = MB + 34816;

  GJ gz{}; VJ vz{};

  hipLaunchKernelGGL(k_seed, dim3(256), dim3(256), 0, stream,
                     A, B, Wp, bphi, xg, ql, rl, ws);

  auto comp = [&](int ia, int ib, int io) {
    double *Ea = Em[ia], *Ga = Gm[ia], *Ha = Hm[ia], *ea = ev[ia], *ha = hv[ia];
    double *Eb = Em[ib], *Gb = Gm[ib], *Hb = Hm[ib], *eb = ev[ib], *hb = hv[ib];
    double *Eo = Em[io], *Go = Gm[io], *Ho = Hm[io], *eo = ev[io], *ho = hv[io];
    // L1: Y = I + Ga@Hb ; J = Ea^T@Hb ; N = Ga@Eb^T ; q1 = Ga@hb
    {
      GJ g0{ Ga, Hb, nullptr, Wb, 256, 1, 256, 1, 256, 1 };
      GJ g1{ Ea, Hb, nullptr, Jb, 1, 256, 256, 1, 256, 0 };
      GJ g2{ Ga, Eb, nullptr, Nb, 256, 1, 1, 256, 256, 0 };
      VJ v0{ Ga, hb, nullptr, q1, 256, 1, 1.0 };
      hipLaunchKernelGGL(k_gemm64, dim3(193), dim3(256), 0, stream, g0, g1, g2, 3, v0, vz, vz);
    }
    // L2: Wb = inv(Wb) via 4 panel launches
    hipLaunchKernelGGL(k_pinv, dim3(64), dim3(256), 0, stream, Wb,  X3b, 0);
    hipLaunchKernelGGL(k_pinv, dim3(64), dim3(256), 0, stream, X3b, Wb,  1);
    hipLaunchKernelGGL(k_pinv, dim3(64), dim3(256), 0, stream, Wb,  X3b, 2);
    hipLaunchKernelGGL(k_pinv, dim3(64), dim3(256), 0, stream, X3b, Wb,  3);
    // L3: P = W@Ea ; T1' = W@N ; w12 = -W@q1 ; u1 = W@ea
    {
      GJ g0{ Wb, Ea, nullptr, Pb, 256, 1, 256, 1, 256, 0 };
      GJ g1{ Wb, Nb, nullptr, T1b, 256, 1, 256, 1, 256, 0 };
      VJ v0{ Wb, q1, nullptr, w12, 256, 1, -1.0 };
      VJ v1{ Wb, ea, nullptr, u1, 256, 1, 1.0 };
      hipLaunchKernelGGL(k_gemm64, dim3(130), dim3(256), 0, stream, g0, g1, gz, 2, v0, v1, vz);
    }
    // L4: Eo = Eb@P ; Go = Gb + Eb@T1' ; Ho = Ha + J@P ;
    //     eo = Eb@w12 + eb ; ho = J@u1 + P^T@hb + ha
    {
      GJ g0{ Eb, Pb, nullptr, Eo, 256, 1, 256, 1, 256, 0 };
      GJ g1{ Eb, T1b, Gb, Go, 256, 1, 256, 1, 256, 0 };
      GJ g2{ Jb, Pb, Ha, Ho, 256, 1, 256, 1, 256, 0 };
      VJ v0{ Eb, w12, eb, eo, 256, 1, 1.0 };
      VJ v1{ Jb, u1, ha, ho, 256, 1, 1.0, Pb, hb, 1, 256, 1.0 };
      hipLaunchKernelGGL(k_gemm64, dim3(194), dim3(256), 0, stream, g0, g1, g2, 3, v0, v1, vz);
    }
  };

  // T2 -> T4 -> T8 -> T16 -> T32 -> T64 -> T72 -> T128 -> T200
  comp(0, 0, 1);   // T2
  comp(1, 1, 0);   // T4
  comp(0, 0, 1);   // T8
  comp(1, 1, 2);   // T16
  comp(2, 2, 0);   // T32
  comp(0, 0, 2);   // T64
  comp(2, 1, 0);   // T72  = T64 o T8
  comp(2, 2, 1);   // T128 = T64 o T64
  comp(1, 0, 2);   // T200 = T128 o T72

  // V_199 = H(T200), v_199 = -h(T200); then the 200th scan step (verified kernels)
  hipLaunchKernelGGL(k_fin2, dim3(256), dim3(256), 0, stream, ws);
  hipLaunchKernelGGL(k_ph1, dim3(64), dim3(256), 0, stream, A, B, ws);
  hipLaunchKernelGGL(k_ph2, dim3(65), dim3(256), 0, stream, A, B, ws, 1);
  hipLaunchKernelGGL(k_ph3, dim3(64), dim3(256), 0, stream, ws, 1);
  hipLaunchKernelGGL(k_fin, dim3(65), dim3(256), 0, stream, Wp, bphi, ws);
  int rows = in_sizes[0] / XD;
  int nblk = rows / 128;
  hipLaunchKernelGGL(k_batch, dim3(nblk), dim3(256), 0, stream, x0, ws, out);
}

// Round 12
// 2476.956 us; speedup vs baseline: 7.0640x; 1.0010x over previous
//
#include <hip/hip_runtime.h>
#include <math.h>

#define KD 256
#define UD 64
#define XD 128

// ws float offsets
#define OFF_V     0
#define OFF_WA    65536
#define OFF_H     131072
#define OFF_G     196608
#define OFF_K0    212992
#define OFF_MI    229376
#define OFF_MP    233472
#define OFF_v     266240
#define OFF_ATV   266496
#define OFF_Z     266752
#define OFF_QG    266816
#define OFF_QD    267072
#define OFF_RD    267328
#define OFF_KV    267392
#define OFF_CV    267456
#define OFF_NKT   267520
// SDA fp64 buffers start at float index 278528 (= double index 139264)
#define DBASE     139264
#define DBUF      65536

__device__ __forceinline__ void inv4(float* D) {
#pragma unroll
  for (int p = 0; p < 4; ++p) {
    float ip = 1.0f / D[p * 4 + p];
#pragma unroll
    for (int i2 = 0; i2 < 4; ++i2)
      if (i2 != p) {
        float f = D[i2 * 4 + p] * ip;
#pragma unroll
        for (int j = 0; j < 4; ++j)
          if (j != p) D[i2 * 4 + j] -= f * D[p * 4 + j];
        D[i2 * 4 + p] = -f;
      }
#pragma unroll
    for (int j = 0; j < 4; ++j)
      if (j != p) D[p * 4 + j] *= ip;
    D[p * 4 + p] = ip;
  }
}

__device__ __forceinline__ void inv4d(double* D) {
#pragma unroll
  for (int p = 0; p < 4; ++p) {
    double ip = 1.0 / D[p * 4 + p];
#pragma unroll
    for (int i2 = 0; i2 < 4; ++i2)
      if (i2 != p) {
        double f = D[i2 * 4 + p] * ip;
#pragma unroll
        for (int j = 0; j < 4; ++j)
          if (j != p) D[i2 * 4 + j] -= f * D[p * 4 + j];
        D[i2 * 4 + p] = -f;
      }
#pragma unroll
    for (int j = 0; j < 4; ++j)
      if (j != p) D[p * 4 + j] *= ip;
    D[p * 4 + p] = ip;
  }
}

#define R16(OP) OP(0) OP(1) OP(2) OP(3) OP(4) OP(5) OP(6) OP(7) OP(8) OP(9) OP(10) OP(11) OP(12) OP(13) OP(14) OP(15)

// ================= seed: init + fp64 seeds + S = Bs@B^T, one launch =================
__global__ __launch_bounds__(256) void k_seed(
    const float* __restrict__ A, const float* __restrict__ B,
    const float* __restrict__ W, const float* __restrict__ bphi,
    const float* __restrict__ xg, const float* __restrict__ qlog,
    const float* __restrict__ rlog, float* __restrict__ ws)
{
  __shared__ double sird[64];     // 1/exp(rlog)
  double* base = (double*)ws + DBASE;
  double* E1 = base + 0 * DBUF;
  double* S  = base + 1 * DBUF;
  double* H1 = base + 2 * DBUF;
  double* MB = base + 14 * DBUF;
  double* B64 = MB;
  double* Bs64 = MB + 16384;
  double* eA = MB + 32768;
  double* hA = MB + 33024;
  const int t = threadIdx.x;
  if (t < 64) sird[t] = 1.0 / exp((double)rlog[t]);
  __syncthreads();
  const int id = blockIdx.x * 256 + t;     // 0..65535
  const int i = id >> 8, j = id & 255;
  E1[id] = (double)A[id];
  H1[id] = (i == j) ? (double)expf(qlog[i]) : 0.0;
  {
    const float* Bi = B + i * 64;
    const float* Bj = B + j * 64;
    double acc = 0.0;
#pragma unroll 8
    for (int m = 0; m < 64; ++m)
      acc = fma((double)Bi[m] * sird[m], (double)Bj[m], acc);
    S[id] = acc;
  }
  if (id < 16384) {
    B64[id] = (double)B[id];
    Bs64[id] = (double)B[id] * sird[id & 63];
  }
  if (id < 256) {
    float acc = 0.f;
    for (int p = 0; p < XD; ++p) acc = fmaf(W[id * XD + p], xg[p], acc);
    float g = acc + bphi[id];
    float qd = expf(qlog[id]);
    ws[OFF_QD + id] = qd; ws[OFF_QG + id] = qd * g;
    eA[id] = 0.0;
    hA[id] = -(double)(qd * g);
  }
  if (id < 64) ws[OFF_RD + id] = expf(rlog[id]);
}

// ================= fp64 batched GEMM/matvec job kernel =================
// R12: single-phase staging — entire 32x256 A-panel + 256x32 B-panel in LDS
// (128KB), ONE __syncthreads, pure-LDS FMA loop. Replaces 8 serial K-chunks
// (8 global-latency round-trips + 16 barriers) with 1.
struct GJ { const double* A; const double* B; const double* C; double* O;
            int sA0, sA1, sB0, sB1, K, addI; };
struct VJ { const double* M1; const double* x; const double* a; double* o;
            int s0, s1; double sgn;
            const double* M2; const double* x2; int s20, s21; double sgn2; };

__global__ __launch_bounds__(256) void k_gemm64(GJ g0, GJ g1, GJ g2, int ng,
                                                VJ v0, VJ v1, VJ v2)
{
  __shared__ double As[32 * 256];   // As[r][k]
  __shared__ double Bs[256 * 32];   // Bs[k][c]
  __shared__ double xs[256];
  __shared__ double xs2[256];
  const int wg = blockIdx.x, t = threadIdx.x;
  if (wg < ng * 64) {
    GJ j = (wg < 64) ? g0 : (wg < 128) ? g1 : g2;
    const int w2 = wg & 63;
    const int tm0 = (w2 >> 3) * 32, tn0 = (w2 & 7) * 32;
    const int rq = t >> 5, c = t & 31;
    // stage full panels (32 loads/thread each, all in flight)
#pragma unroll
    for (int q = 0; q < 32; ++q) {
      int idx = q * 256 + t;
      int r = idx >> 8, k2 = idx & 255;
      As[r * 256 + k2] = j.A[(long)(tm0 + r) * j.sA0 + (long)k2 * j.sA1];
      int kb = idx >> 5, cb = idx & 31;
      Bs[kb * 32 + cb] = j.B[(long)kb * j.sB0 + (long)(tn0 + cb) * j.sB1];
    }
    __syncthreads();
    double a0 = 0, a1 = 0, a2 = 0, a3 = 0;
    const double* Ar0 = &As[(rq * 4 + 0) * 256];
    const double* Ar1 = &As[(rq * 4 + 1) * 256];
    const double* Ar2 = &As[(rq * 4 + 2) * 256];
    const double* Ar3 = &As[(rq * 4 + 3) * 256];
#pragma unroll 8
    for (int kk = 0; kk < 256; ++kk) {
      double b = Bs[kk * 32 + c];
      a0 = fma(Ar0[kk], b, a0);
      a1 = fma(Ar1[kk], b, a1);
      a2 = fma(Ar2[kk], b, a2);
      a3 = fma(Ar3[kk], b, a3);
    }
    const int n = tn0 + c;
    double av[4] = {a0, a1, a2, a3};
#pragma unroll
    for (int i2 = 0; i2 < 4; ++i2) {
      int m = tm0 + rq * 4 + i2;
      double v = av[i2];
      if (j.C) v += j.C[m * 256 + n];
      if (j.addI && m == n) v += 1.0;
      j.O[m * 256 + n] = v;
    }
  } else {
    const int vi = wg - ng * 64;
    VJ j = (vi == 0) ? v0 : (vi == 1) ? v1 : v2;
    xs[t] = j.x[t];
    if (j.M2) xs2[t] = j.x2[t];
    __syncthreads();
    double acc = 0;
#pragma unroll 8
    for (int k2 = 0; k2 < 256; ++k2)
      acc = fma(j.M1[(long)t * j.s0 + (long)k2 * j.s1], xs[k2], acc);
    double o = j.sgn * acc;
    if (j.M2) {
      double acc2 = 0;
#pragma unroll 8
      for (int k2 = 0; k2 < 256; ++k2)
        acc2 = fma(j.M2[(long)t * j.s20 + (long)k2 * j.s21], xs2[k2], acc2);
      o += j.sgn2 * acc2;
    }
    if (j.a) o += j.a[t];
    j.o[t] = o;
  }
}

// ================= fp64 256x256 inverse: one PANEL step (64 WGs, ping-pong) ====
// Verified R10/R11. Blocked unpivoted Gauss-Jordan, panel width 64, 4 launches.
__global__ __launch_bounds__(256) void k_pinv(const double* __restrict__ Yc,
                                              double* __restrict__ Yn, int pk)
{
  const int w = blockIdx.x, t = threadIdx.x;
  const int bi = w >> 3, bj = w & 7;
  const int p0 = pk * 64, pb = pk * 2;
  const int r0 = bi * 32, c0 = bj * 32;

  __shared__ double sDI[64 * 65];
  __shared__ double sC [32 * 66];
  __shared__ double sR [64 * 34];
  __shared__ double sL [32 * 66];
  __shared__ double sU [64 * 34];
  __shared__ double sPR[4 * 68];
  __shared__ double sF [64 * 5];

  for (int q = 0; q < 8; ++q) { int lin = q * 256 + t; int r = lin >> 6, m = lin & 63; sC[r * 66 + m] = Yc[(r0 + r) * 256 + p0 + m]; }
  for (int q = 0; q < 8; ++q) { int lin = q * 256 + t; int m = lin >> 5, c = lin & 31; sR[m * 34 + c] = Yc[(p0 + m) * 256 + c0 + c]; }

  const int i = t & 63, cg = t >> 6;
  double rr[16];
#pragma unroll
  for (int q = 0; q < 16; ++q) rr[q] = Yc[(p0 + i) * 256 + p0 + cg * 16 + q];
  for (int k = 0; k < 16; ++k) {
    const int prw = i - 4 * k;
    const bool inblk = (unsigned)prw < 4u;
    if (inblk) {
#pragma unroll
      for (int q = 0; q < 16; ++q) sPR[prw * 68 + cg * 16 + q] = rr[q];
    }
    if (cg == (k >> 2)) {
      const int b = (k & 3) * 4;
      sF[i * 5 + 0] = rr[b + 0]; sF[i * 5 + 1] = rr[b + 1];
      sF[i * 5 + 2] = rr[b + 2]; sF[i * 5 + 3] = rr[b + 3];
    }
    __syncthreads();
    double D[16];
#pragma unroll
    for (int q = 0; q < 4; ++q) {
      D[q * 4 + 0] = sPR[q * 68 + 4 * k + 0];
      D[q * 4 + 1] = sPR[q * 68 + 4 * k + 1];
      D[q * 4 + 2] = sPR[q * 68 + 4 * k + 2];
      D[q * 4 + 3] = sPR[q * 68 + 4 * k + 3];
    }
    inv4d(D);
    double f0 = sF[i * 5 + 0], f1 = sF[i * 5 + 1], f2 = sF[i * 5 + 2], f3 = sF[i * 5 + 3];
    double g0, g1, g2, g3;
    if (inblk) {
      g0 = prw == 0 ? D[0] : prw == 1 ? D[4] : prw == 2 ? D[8]  : D[12];
      g1 = prw == 0 ? D[1] : prw == 1 ? D[5] : prw == 2 ? D[9]  : D[13];
      g2 = prw == 0 ? D[2] : prw == 1 ? D[6] : prw == 2 ? D[10] : D[14];
      g3 = prw == 0 ? D[3] : prw == 1 ? D[7] : prw == 2 ? D[11] : D[15];
    } else {
      g0 = f0 * D[0] + f1 * D[4] + f2 * D[8]  + f3 * D[12];
      g1 = f0 * D[1] + f1 * D[5] + f2 * D[9]  + f3 * D[13];
      g2 = f0 * D[2] + f1 * D[6] + f2 * D[10] + f3 * D[14];
      g3 = f0 * D[3] + f1 * D[7] + f2 * D[11] + f3 * D[15];
    }
#pragma unroll
    for (int q = 0; q < 16; ++q) {
      double pr0 = sPR[0 * 68 + cg * 16 + q];
      double pr1 = sPR[1 * 68 + cg * 16 + q];
      double pr2 = sPR[2 * 68 + cg * 16 + q];
      double pr3 = sPR[3 * 68 + cg * 16 + q];
      double n = fma(g0, pr0, fma(g1, pr1, fma(g2, pr2, g3 * pr3)));
      rr[q] = inblk ? n : rr[q] - n;
    }
    if (cg == (k >> 2)) {
      const int b = (k & 3) * 4;
      rr[b + 0] = inblk ? g0 : -g0; rr[b + 1] = inblk ? g1 : -g1;
      rr[b + 2] = inblk ? g2 : -g2; rr[b + 3] = inblk ? g3 : -g3;
    }
    __syncthreads();
  }
#pragma unroll
  for (int q = 0; q < 16; ++q) sDI[i * 65 + cg * 16 + q] = rr[q];
  __syncthreads();

  {
    const int r = t >> 3, u0 = (t & 7) * 8;
    double acc[8];
#pragma unroll
    for (int u = 0; u < 8; ++u) acc[u] = 0.0;
#pragma unroll 4
    for (int m = 0; m < 64; ++m) {
      double cv = sC[r * 66 + m];
#pragma unroll
      for (int u = 0; u < 8; ++u) acc[u] = fma(cv, sDI[m * 65 + u0 + u], acc[u]);
    }
#pragma unroll
    for (int u = 0; u < 8; ++u) sL[r * 66 + u0 + u] = acc[u];
  }
  {
    const int qrow = t >> 2, c4 = (t & 3) * 8;
    double acc[8];
#pragma unroll
    for (int u = 0; u < 8; ++u) acc[u] = 0.0;
#pragma unroll 4
    for (int m = 0; m < 64; ++m) {
      double dv = sDI[qrow * 65 + m];
#pragma unroll
      for (int u = 0; u < 8; ++u) acc[u] = fma(dv, sR[m * 34 + c4 + u], acc[u]);
    }
#pragma unroll
    for (int u = 0; u < 8; ++u) sU[qrow * 34 + c4 + u] = acc[u];
  }
  __syncthreads();

  const bool rip = (bi == pb || bi == pb + 1);
  const bool cip = (bj == pb || bj == pb + 1);
  const int r = t >> 3, cc4 = (t & 7) * 4;
#pragma unroll
  for (int u = 0; u < 4; ++u) {
    const int c = cc4 + u;
    double outv;
    if (rip && cip) {
      outv = sDI[((bi - pb) * 32 + r) * 65 + (bj - pb) * 32 + c];
    } else if (cip) {
      outv = -sL[r * 66 + (bj - pb) * 32 + c];
    } else if (rip) {
      outv = sU[((bi - pb) * 32 + r) * 34 + c];
    } else {
      double acc = Yc[(r0 + r) * 256 + c0 + c];
#pragma unroll 8
      for (int q = 0; q < 64; ++q) acc = fma(-sC[r * 66 + q], sU[q * 34 + c], acc);
      outv = acc;
    }
    Yn[(r0 + r) * 256 + c0 + c] = outv;
  }
}

// ================= single Riccati step (tail; ph1 reads fp64 V199/v199 directly) ==
__global__ __launch_bounds__(256) void k_ph1(
    const float* __restrict__ A, const float* __restrict__ B,
    float* __restrict__ ws)
{
  const int u = blockIdx.x, t = threadIdx.x;
  const int sb = u & 7, hb = u >> 3;
  const int rb = sb * 32, cb0 = hb * 32, m0 = hb * 8;
  float* WAg = ws + OFF_WA;
  const double* V64 = (double*)ws + DBASE + 8 * DBUF;              // Hm[2] = V_199
  const double* h64 = (double*)ws + DBASE + 14 * DBUF + 34048;     // hv[2]; v_199 = -h

  __shared__ float sVt[256 * 36];
  __shared__ float sA [256 * 36];
  __shared__ float sBsl[256 * 8];
  __shared__ float sBr[32 * 64];
  __shared__ float svv[256];
  __shared__ float sVB[32 * 9];
  __shared__ float sRed[8 * 36];

  for (int q = 0; q < 8; ++q) {
    int idx = q * 256 + t; int p = idx >> 3, r4 = (idx & 7) * 4;
    sVt[p * 36 + r4 + 0] = (float)V64[p * 256 + rb + r4 + 0];
    sVt[p * 36 + r4 + 1] = (float)V64[p * 256 + rb + r4 + 1];
    sVt[p * 36 + r4 + 2] = (float)V64[p * 256 + rb + r4 + 2];
    sVt[p * 36 + r4 + 3] = (float)V64[p * 256 + rb + r4 + 3];
  }
  for (int q = 0; q < 8; ++q) {
    int idx = q * 256 + t; int p = idx >> 3, r4 = (idx & 7) * 4;
    *(float4*)&sA[p * 36 + r4] = *(const float4*)(A + p * KD + cb0 + r4);
  }
  for (int q = 0; q < 2; ++q) {
    int idx = q * 256 + t; int p = idx >> 1, j4 = (idx & 1) * 4;
    *(float4*)&sBsl[p * 8 + j4] = *(const float4*)(B + p * UD + m0 + j4);
  }
  for (int q = 0; q < 2; ++q) {
    int idx = q * 256 + t; int r = idx >> 4, a4 = (idx & 15) * 4;
    *(float4*)&sBr[r * 64 + a4] = *(const float4*)(B + (rb + r) * UD + a4);
  }
  svv[t] = -(float)h64[t];
  __syncthreads();

  const int j = t & 31, rq = t >> 5;
  float4 acc = {0.f, 0.f, 0.f, 0.f};
  float avb0 = 0.f, avb1 = 0.f, avb2 = 0.f, avb3 = 0.f;
  const bool dovb = (j < 8);
#pragma unroll 8
  for (int p = 0; p < KD; ++p) {
    float4 v4 = *(const float4*)&sVt[p * 36 + rq * 4];
    float a = sA[p * 36 + j];
    acc.x = fmaf(v4.x, a, acc.x);
    acc.y = fmaf(v4.y, a, acc.y);
    acc.z = fmaf(v4.z, a, acc.z);
    acc.w = fmaf(v4.w, a, acc.w);
    if (dovb) {
      float b = sBsl[p * 8 + j];
      avb0 = fmaf(v4.x, b, avb0);
      avb1 = fmaf(v4.y, b, avb1);
      avb2 = fmaf(v4.z, b, avb2);
      avb3 = fmaf(v4.w, b, avb3);
    }
  }
  WAg[(rb + 4 * rq + 0) * KD + cb0 + j] = acc.x;
  WAg[(rb + 4 * rq + 1) * KD + cb0 + j] = acc.y;
  WAg[(rb + 4 * rq + 2) * KD + cb0 + j] = acc.z;
  WAg[(rb + 4 * rq + 3) * KD + cb0 + j] = acc.w;
  if (dovb) {
    sVB[(4 * rq + 0) * 9 + j] = avb0;
    sVB[(4 * rq + 1) * 9 + j] = avb1;
    sVB[(4 * rq + 2) * 9 + j] = avb2;
    sVB[(4 * rq + 3) * 9 + j] = avb3;
  }
  if (sb == 0) {
    int c = t & 31, part = t >> 5;
    float acc2 = 0.f;
#pragma unroll 8
    for (int p = part * 32; p < part * 32 + 32; ++p) acc2 = fmaf(sA[p * 36 + c], svv[p], acc2);
    sRed[part * 36 + c] = acc2;
  }
  if (sb == 1 && t < 64) {
    int jz = t & 7, part = t >> 3;
    float acc2 = 0.f;
#pragma unroll 8
    for (int p = part * 32; p < part * 32 + 32; ++p) acc2 = fmaf(sBsl[p * 8 + jz], svv[p], acc2);
    sRed[part * 36 + jz] = acc2;
  }
  __syncthreads();
  {
    int a = t & 63, j2 = (t >> 6) * 2;
    float mp0 = 0.f, mp1 = 0.f;
#pragma unroll 8
    for (int r = 0; r < 32; ++r) {
      float bv = sBr[r * 64 + a];
      mp0 = fmaf(bv, sVB[r * 9 + j2 + 0], mp0);
      mp1 = fmaf(bv, sVB[r * 9 + j2 + 1], mp1);
    }
    ws[OFF_MP + sb * 4096 + a * 64 + m0 + j2 + 0] = mp0;
    ws[OFF_MP + sb * 4096 + a * 64 + m0 + j2 + 1] = mp1;
  }
  if (sb == 0 && t < 32) {
    float a2 = 0.f;
#pragma unroll
    for (int pt = 0; pt < 8; ++pt) a2 += sRed[pt * 36 + t];
    ws[OFF_ATV + cb0 + t] = a2;
  }
  if (sb == 1 && t < 8) {
    float a2 = 0.f;
#pragma unroll
    for (int pt = 0; pt < 8; ++pt) a2 += sRed[pt * 36 + t];
    ws[OFF_Z + m0 + t] = a2;
  }
}

__global__ __launch_bounds__(256) void k_ph2(
    const float* __restrict__ A, const float* __restrict__ B,
    float* __restrict__ ws, int last)
{
  const int w = blockIdx.x, t = threadIdx.x;
  const int u = w - 1;
  float* WAg = ws + OFF_WA;
  float* MI  = ws + OFF_MI;

  __shared__ float sWA[256 * 33];
  __shared__ float sA [256 * 36];
  __shared__ float sBsl[256 * 8];
  __shared__ float scr[608];
  __shared__ float wred[256];

  if (w == 0) {
    float* sPR = scr;
    float* sF  = scr + 280;
    const int i = t & 63, cg = t >> 6;
    const float rdi = ws[OFF_RD + i];
    float rr[16];
    {
      float4 s0 = {0,0,0,0}, s1 = {0,0,0,0}, s2 = {0,0,0,0}, s3 = {0,0,0,0};
#pragma unroll
      for (int sb2 = 0; sb2 < 8; ++sb2) {
        const float* mp = ws + OFF_MP + sb2 * 4096 + i * 64 + cg * 16;
        float4 a0 = *(const float4*)(mp + 0);
        float4 a1 = *(const float4*)(mp + 4);
        float4 a2 = *(const float4*)(mp + 8);
        float4 a3 = *(const float4*)(mp + 12);
        s0.x += a0.x; s0.y += a0.y; s0.z += a0.z; s0.w += a0.w;
        s1.x += a1.x; s1.y += a1.y; s1.z += a1.z; s1.w += a1.w;
        s2.x += a2.x; s2.y += a2.y; s2.z += a2.z; s2.w += a2.w;
        s3.x += a3.x; s3.y += a3.y; s3.z += a3.z; s3.w += a3.w;
      }
      rr[0]=s0.x; rr[1]=s0.y; rr[2]=s0.z; rr[3]=s0.w;
      rr[4]=s1.x; rr[5]=s1.y; rr[6]=s1.z; rr[7]=s1.w;
      rr[8]=s2.x; rr[9]=s2.y; rr[10]=s2.z; rr[11]=s2.w;
      rr[12]=s3.x; rr[13]=s3.y; rr[14]=s3.z; rr[15]=s3.w;
#define DIAG(j) rr[j] += (cg * 16 + j == i) ? rdi : 0.f;
      R16(DIAG)
#undef DIAG
    }
    for (int k = 0; k < 16; ++k) {
      const int prw = i - 4 * k;
      const bool inblk = (unsigned)prw < 4u;
      if (inblk) {
#define ST(j) sPR[prw * 68 + cg * 16 + j] = rr[j];
        R16(ST)
#undef ST
      }
      if (cg == (k >> 2)) {
        switch (k & 3) {
          case 0: sF[i*5+0]=rr[0];  sF[i*5+1]=rr[1];  sF[i*5+2]=rr[2];  sF[i*5+3]=rr[3];  break;
          case 1: sF[i*5+0]=rr[4];  sF[i*5+1]=rr[5];  sF[i*5+2]=rr[6];  sF[i*5+3]=rr[7];  break;
          case 2: sF[i*5+0]=rr[8];  sF[i*5+1]=rr[9];  sF[i*5+2]=rr[10]; sF[i*5+3]=rr[11]; break;
          default:sF[i*5+0]=rr[12]; sF[i*5+1]=rr[13]; sF[i*5+2]=rr[14]; sF[i*5+3]=rr[15]; break;
        }
      }
      __syncthreads();
      float D[16];
#pragma unroll
      for (int q = 0; q < 4; ++q) {
        D[q*4+0] = sPR[q*68 + 4*k + 0];
        D[q*4+1] = sPR[q*68 + 4*k + 1];
        D[q*4+2] = sPR[q*68 + 4*k + 2];
        D[q*4+3] = sPR[q*68 + 4*k + 3];
      }
      inv4(D);
      float f0 = sF[i*5+0], f1 = sF[i*5+1], f2 = sF[i*5+2], f3 = sF[i*5+3];
      float g0, g1, g2, g3;
      if (inblk) {
        g0 = prw==0?D[0]:prw==1?D[4]:prw==2?D[8]:D[12];
        g1 = prw==0?D[1]:prw==1?D[5]:prw==2?D[9]:D[13];
        g2 = prw==0?D[2]:prw==1?D[6]:prw==2?D[10]:D[14];
        g3 = prw==0?D[3]:prw==1?D[7]:prw==2?D[11]:D[15];
      } else {
        g0 = f0*D[0] + f1*D[4] + f2*D[8]  + f3*D[12];
        g1 = f0*D[1] + f1*D[5] + f2*D[9]  + f3*D[13];
        g2 = f0*D[2] + f1*D[6] + f2*D[10] + f3*D[14];
        g3 = f0*D[3] + f1*D[7] + f2*D[11] + f3*D[15];
      }
#define CHUNK(c4)                                                         \
      {                                                                   \
        float4 p0 = *(const float4*)&sPR[0 * 68 + cg * 16 + (c4) * 4];    \
        float4 p1 = *(const float4*)&sPR[1 * 68 + cg * 16 + (c4) * 4];    \
        float4 p2 = *(const float4*)&sPR[2 * 68 + cg * 16 + (c4) * 4];    \
        float4 p3 = *(const float4*)&sPR[3 * 68 + cg * 16 + (c4) * 4];    \
        float n0 = fmaf(g0,p0.x, fmaf(g1,p1.x, fmaf(g2,p2.x, g3*p3.x)));  \
        float n1 = fmaf(g0,p0.y, fmaf(g1,p1.y, fmaf(g2,p2.y, g3*p3.y)));  \
        float n2 = fmaf(g0,p0.z, fmaf(g1,p1.z, fmaf(g2,p2.z, g3*p3.z)));  \
        float n3 = fmaf(g0,p0.w, fmaf(g1,p1.w, fmaf(g2,p2.w, g3*p3.w)));  \
        if (inblk) { rr[(c4)*4+0]=n0; rr[(c4)*4+1]=n1; rr[(c4)*4+2]=n2; rr[(c4)*4+3]=n3; } \
        else { rr[(c4)*4+0]-=n0; rr[(c4)*4+1]-=n1; rr[(c4)*4+2]-=n2; rr[(c4)*4+3]-=n3; }   \
      }
      CHUNK(0) CHUNK(1) CHUNK(2) CHUNK(3)
#undef CHUNK
      if (cg == (k >> 2)) {
        switch (k & 3) {
          case 0: rr[0] = inblk? g0:-g0; rr[1] = inblk? g1:-g1; rr[2] = inblk? g2:-g2; rr[3] = inblk? g3:-g3; break;
          case 1: rr[4] = inblk? g0:-g0; rr[5] = inblk? g1:-g1; rr[6] = inblk? g2:-g2; rr[7] = inblk? g3:-g3; break;
          case 2: rr[8] = inblk? g0:-g0; rr[9] = inblk? g1:-g1; rr[10]= inblk? g2:-g2; rr[11]= inblk? g3:-g3; break;
          default:rr[12]= inblk? g0:-g0; rr[13]= inblk? g1:-g1; rr[14]= inblk? g2:-g2; rr[15]= inblk? g3:-g3; break;
        }
      }
      __syncthreads();
    }
    *(float4*)(MI + i * 64 + cg * 16 + 0)  = *(float4*)&rr[0];
    *(float4*)(MI + i * 64 + cg * 16 + 4)  = *(float4*)&rr[4];
    *(float4*)(MI + i * 64 + cg * 16 + 8)  = *(float4*)&rr[8];
    *(float4*)(MI + i * 64 + cg * 16 + 12) = *(float4*)&rr[12];
    if (last) {
      float p2 = 0.f;
#define KV(j) p2 = fmaf(rr[j], ws[OFF_Z + cg * 16 + j], p2);
      R16(KV)
#undef KV
      wred[i * 4 + cg] = p2;
      __syncthreads();
      if (t < 64) ws[OFF_KV + t] = wred[t*4+0] + wred[t*4+1] + wred[t*4+2] + wred[t*4+3];
    }
  } else {
    const int sb = u & 7, hb = u >> 3;
    const int rb = sb * 32, cb0 = hb * 32, m0 = hb * 8;
    for (int q = 0; q < 8; ++q) {
      int idx = q * 256 + t;
      int p = idx >> 3, c4 = (idx & 7) * 4;
      float4 v4 = *(const float4*)(WAg + p * KD + rb + c4);
      sWA[p * 33 + c4 + 0] = v4.x;
      sWA[p * 33 + c4 + 1] = v4.y;
      sWA[p * 33 + c4 + 2] = v4.z;
      sWA[p * 33 + c4 + 3] = v4.w;
    }
    for (int q = 0; q < 8; ++q) {
      int idx = q * 256 + t; int p = idx >> 3, r4 = (idx & 7) * 4;
      *(float4*)&sA[p * 36 + r4] = *(const float4*)(A + p * KD + cb0 + r4);
    }
    for (int q = 0; q < 2; ++q) {
      int idx = q * 256 + t; int p = idx >> 1, j4 = (idx & 1) * 4;
      *(float4*)&sBsl[p * 8 + j4] = *(const float4*)(B + p * UD + m0 + j4);
    }
    __syncthreads();
    const int c = t & 31, q = t >> 5;
    float4 hacc = {0.f, 0.f, 0.f, 0.f};
    float gacc = 0.f;
#pragma unroll 8
    for (int p = 0; p < KD; ++p) {
      float wv = sWA[p * 33 + c];
      float4 a4 = *(const float4*)&sA[p * 36 + 4 * q];
      float bq = sBsl[p * 8 + q];
      hacc.x = fmaf(a4.x, wv, hacc.x);
      hacc.y = fmaf(a4.y, wv, hacc.y);
      hacc.z = fmaf(a4.z, wv, hacc.z);
      hacc.w = fmaf(a4.w, wv, hacc.w);
      gacc = fmaf(bq, wv, gacc);
    }
    float* Hm = ws + OFF_H;
    float* Gm = ws + OFF_G;
    Hm[(cb0 + 4*q + 0) * KD + rb + c] = hacc.x;
    Hm[(cb0 + 4*q + 1) * KD + rb + c] = hacc.y;
    Hm[(cb0 + 4*q + 2) * KD + rb + c] = hacc.z;
    Hm[(cb0 + 4*q + 3) * KD + rb + c] = hacc.w;
    Gm[(m0 + q) * KD + rb + c] = gacc;
  }
}

__global__ __launch_bounds__(256) void k_ph3(float* __restrict__ ws, int last)
{
  const int u = blockIdx.x, t = threadIdx.x;
  const int sb = u & 7, hb = u >> 3;
  const int cb2 = sb * 32, rb2 = hb * 32;
  float* V  = ws + OFF_V;
  float* Hm = ws + OFF_H;
  float* Gm = ws + OFF_G;

  __shared__ float sMI_[64 * 65];
  __shared__ float sGb [64 * 36];
  __shared__ float sGc [64 * 36];
  __shared__ float sKs [64 * 33];
  __shared__ float sZ[64];
  __shared__ float sQd[32];
  __shared__ float sRed[8 * 36];

  for (int q = 0; q < 16; ++q) { int idx = q * 256 + t; int row = idx >> 6, col = idx & 63; sMI_[row * 65 + col] = ws[OFF_MI + idx]; }
  for (int q = 0; q < 2; ++q) {
    int idx = q * 256 + t; int m = idx >> 3, c4 = (idx & 7) * 4;
    float4 g4 = *(const float4*)(Gm + m * KD + cb2 + c4);
    sGb[m * 36 + c4 + 0] = g4.x; sGb[m * 36 + c4 + 1] = g4.y;
    sGb[m * 36 + c4 + 2] = g4.z; sGb[m * 36 + c4 + 3] = g4.w;
  }
  for (int q = 0; q < 2; ++q) {
    int idx = q * 256 + t; int m = idx >> 3, c4 = (idx & 7) * 4;
    float4 g4 = *(const float4*)(Gm + m * KD + rb2 + c4);
    sGc[m * 36 + c4 + 0] = g4.x; sGc[m * 36 + c4 + 1] = g4.y;
    sGc[m * 36 + c4 + 2] = g4.z; sGc[m * 36 + c4 + 3] = g4.w;
  }
  if (t < 64) sZ[t] = ws[OFF_Z + t];
  if (t < 32) sQd[t] = ws[OFF_QD + rb2 + t];
  __syncthreads();
  {
    const int m = t & 63, wv = t >> 6;
    float k0=0,k1=0,k2=0,k3=0,k4=0,k5=0,k6=0,k7=0;
#pragma unroll 4
    for (int p = 0; p < UD; ++p) {
      float mi = sMI_[m * 65 + p];
      float4 ga  = *(const float4*)&sGb[p * 36 + wv * 8 + 0];
      float4 gb2 = *(const float4*)&sGb[p * 36 + wv * 8 + 4];
      k0 = fmaf(mi, ga.x, k0); k1 = fmaf(mi, ga.y, k1);
      k2 = fmaf(mi, ga.z, k2); k3 = fmaf(mi, ga.w, k3);
      k4 = fmaf(mi, gb2.x, k4); k5 = fmaf(mi, gb2.y, k5);
      k6 = fmaf(mi, gb2.z, k6); k7 = fmaf(mi, gb2.w, k7);
    }
    sKs[m * 33 + wv * 8 + 0] = k0; sKs[m * 33 + wv * 8 + 1] = k1;
    sKs[m * 33 + wv * 8 + 2] = k2; sKs[m * 33 + wv * 8 + 3] = k3;
    sKs[m * 33 + wv * 8 + 4] = k4; sKs[m * 33 + wv * 8 + 5] = k5;
    sKs[m * 33 + wv * 8 + 6] = k6; sKs[m * 33 + wv * 8 + 7] = k7;
    if (last && hb == 0) {
      float* K0 = ws + OFF_K0;
      K0[m * KD + cb2 + wv * 8 + 0] = k0; K0[m * KD + cb2 + wv * 8 + 1] = k1;
      K0[m * KD + cb2 + wv * 8 + 2] = k2; K0[m * KD + cb2 + wv * 8 + 3] = k3;
      K0[m * KD + cb2 + wv * 8 + 4] = k4; K0[m * KD + cb2 + wv * 8 + 5] = k5;
      K0[m * KD + cb2 + wv * 8 + 6] = k6; K0[m * KD + cb2 + wv * 8 + 7] = k7;
    }
  }
  __syncthreads();
  {
    const int c = t & 31, q = t >> 5;
    float a0 = 0.f, a1 = 0.f, a2 = 0.f, a3 = 0.f;
#pragma unroll 8
    for (int m = 0; m < UD; ++m) {
      float4 g4 = *(const float4*)&sGc[m * 36 + 4 * q];
      float km = sKs[m * 33 + c];
      a0 = fmaf(g4.x, km, a0); a1 = fmaf(g4.y, km, a1);
      a2 = fmaf(g4.z, km, a2); a3 = fmaf(g4.w, km, a3);
    }
    const int cc = cb2 + c;
    int r = rb2 + 4 * q;
    float h0 = Hm[(r+0) * KD + cc], h1 = Hm[(r+1) * KD + cc];
    float h2 = Hm[(r+2) * KD + cc], h3 = Hm[(r+3) * KD + cc];
    V[(r+0) * KD + cc] = h0 - a0 + ((r+0 == cc) ? sQd[4*q+0] : 0.f);
    V[(r+1) * KD + cc] = h1 - a1 + ((r+1 == cc) ? sQd[4*q+1] : 0.f);
    V[(r+2) * KD + cc] = h2 - a2 + ((r+2 == cc) ? sQd[4*q+2] : 0.f);
    V[(r+3) * KD + cc] = h3 - a3 + ((r+3 == cc) ? sQd[4*q+3] : 0.f);
  }
  if (hb == 0) {
    int c = t & 31, part = t >> 5;
    float acc2 = 0.f;
#pragma unroll
    for (int m = part * 8; m < part * 8 + 8; ++m) acc2 = fmaf(sKs[m * 33 + c], sZ[m], acc2);
    sRed[part * 36 + c] = acc2;
    __syncthreads();
    if (t < 32)  {
      float s2 = 0.f;
#pragma unroll
      for (int pt = 0; pt < 8; ++pt) s2 += sRed[pt * 36 + t];
      ws[OFF_v + cb2 + t] = ws[OFF_ATV + cb2 + t] - s2 + ws[OFF_QG + cb2 + t];
    }
  }
}

__global__ __launch_bounds__(256) void k_fin(
    const float* __restrict__ W, const float* __restrict__ bphi,
    float* __restrict__ ws)
{
  const int w = blockIdx.x, t = threadIdx.x;
  const float* K0 = ws + OFF_K0;
  if (w >= 1 && t < 128) {
    int j = t & 63, kk = 2 * (w - 1) + (t >> 6);
    float acc = 0.f;
#pragma unroll 8
    for (int i = 0; i < KD; ++i) acc = fmaf(K0[j * KD + i], W[i * XD + kk], acc);
    ws[OFF_NKT + kk * UD + j] = -acc;
  }
  if (w == 0 && t < UD) {
    float acc = 0.f;
#pragma unroll 8
    for (int i = 0; i < KD; ++i) acc = fmaf(K0[t * KD + i], bphi[i], acc);
    ws[OFF_CV + t] = ws[OFF_KV + t] - acc;
  }
}

__global__ __launch_bounds__(256) void k_batch(const float* __restrict__ x0,
                                               const float* __restrict__ ws,
                                               float* __restrict__ out)
{
  __shared__ float kt[XD][UD];
  __shared__ float cvs[UD];
  const int t = threadIdx.x;
  {
    const float4* src = (const float4*)(ws + OFF_NKT);
    float4* dst = (float4*)kt;
#pragma unroll
    for (int idx = 0; idx < (XD * UD / 4) / 256; ++idx)
      dst[t + idx * 256] = src[t + idx * 256];
  }
  if (t < UD) cvs[t] = ws[OFF_CV + t];
  __syncthreads();

  const int ty = t >> 4, tx = t & 15;

#define FMA4(acc, s, f4)                      \
  acc.x = fmaf((s), (f4).x, acc.x);           \
  acc.y = fmaf((s), (f4).y, acc.y);           \
  acc.z = fmaf((s), (f4).z, acc.z);           \
  acc.w = fmaf((s), (f4).w, acc.w);

  float4 cq = *(float4*)&cvs[tx * 4];
#pragma unroll
  for (int half = 0; half < 2; ++half) {
    const long r0 = (long)blockIdx.x * 128 + half * 64 + ty * 4;
    const float* xp = x0 + r0 * XD;
    float4 acc0 = {0,0,0,0}, acc1 = {0,0,0,0}, acc2 = {0,0,0,0}, acc3 = {0,0,0,0};
#pragma unroll 2
    for (int k = 0; k < XD; k += 4) {
      float4 x_0 = *(const float4*)(xp + 0 * XD + k);
      float4 x_1 = *(const float4*)(xp + 1 * XD + k);
      float4 x_2 = *(const float4*)(xp + 2 * XD + k);
      float4 x_3 = *(const float4*)(xp + 3 * XD + k);
      float4 k_0 = *(const float4*)&kt[k + 0][tx * 4];
      float4 k_1 = *(const float4*)&kt[k + 1][tx * 4];
      float4 k_2 = *(const float4*)&kt[k + 2][tx * 4];
      float4 k_3 = *(const float4*)&kt[k + 3][tx * 4];
      FMA4(acc0, x_0.x, k_0) FMA4(acc0, x_0.y, k_1) FMA4(acc0, x_0.z, k_2) FMA4(acc0, x_0.w, k_3)
      FMA4(acc1, x_1.x, k_0) FMA4(acc1, x_1.y, k_1) FMA4(acc1, x_1.z, k_2) FMA4(acc1, x_1.w, k_3)
      FMA4(acc2, x_2.x, k_0) FMA4(acc2, x_2.y, k_1) FMA4(acc2, x_2.z, k_2) FMA4(acc2, x_2.w, k_3)
      FMA4(acc3, x_3.x, k_0) FMA4(acc3, x_3.y, k_1) FMA4(acc3, x_3.z, k_2) FMA4(acc3, x_3.w, k_3)
    }
    acc0.x += cq.x; acc0.y += cq.y; acc0.z += cq.z; acc0.w += cq.w;
    acc1.x += cq.x; acc1.y += cq.y; acc1.z += cq.z; acc1.w += cq.w;
    acc2.x += cq.x; acc2.y += cq.y; acc2.z += cq.z; acc2.w += cq.w;
    acc3.x += cq.x; acc3.y += cq.y; acc3.z += cq.z; acc3.w += cq.w;
    *(float4*)(out + (r0 + 0) * UD + tx * 4) = acc0;
    *(float4*)(out + (r0 + 1) * UD + tx * 4) = acc1;
    *(float4*)(out + (r0 + 2) * UD + tx * 4) = acc2;
    *(float4*)(out + (r0 + 3) * UD + tx * 4) = acc3;
  }
}

extern "C" void kernel_launch(void* const* d_in, const int* in_sizes, int n_in,
                              void* d_out, int out_size, void* d_ws, size_t ws_size,
                              hipStream_t stream) {
  const float* x0   = (const float*)d_in[0];
  const float* Wp   = (const float*)d_in[1];
  const float* bphi = (const float*)d_in[2];
  const float* xg   = (const float*)d_in[3];
  const float* A    = (const float*)d_in[4];
  const float* B    = (const float*)d_in[5];
  const float* ql   = (const float*)d_in[6];
  const float* rl   = (const float*)d_in[7];
  float* ws  = (float*)d_ws;
  float* out = (float*)d_out;

  double* base = (double*)d_ws + DBASE;
  double* Em[3] = { base + 0*DBUF, base + 3*DBUF, base + 6*DBUF };
  double* Gm[3] = { base + 1*DBUF, base + 4*DBUF, base + 7*DBUF };
  double* Hm[3] = { base + 2*DBUF, base + 5*DBUF, base + 8*DBUF };
  double* Wb  = base + 9*DBUF;
  double* Pb  = base + 10*DBUF;
  double* T1b = base + 11*DBUF;
  double* Jb  = base + 12*DBUF;    // J = Ea^T @ Hb
  double* X3b = base + 13*DBUF;    // pinv ping-pong scratch
  double* Nb  = (double*)d_ws + 32768;  // N = Ga@Eb^T (aliases fp32 WA/H region)
  double* MB  = base + 14*DBUF;
  double* ev[3] = { MB + 32768, MB + 33280, MB + 33792 };
  double* hv[3] = { MB + 33024, MB + 33536, MB + 34048 };
  double* q1  = MB + 34304;
  double* w12 = MB + 34560;
  double* u1  = MB + 34816;

  GJ gz{}; VJ vz{};

  hipLaunchKernelGGL(k_seed, dim3(256), dim3(256), 0, stream,
                     A, B, Wp, bphi, xg, ql, rl, ws);

  auto comp = [&](int ia, int ib, int io) {
    double *Ea = Em[ia], *Ga = Gm[ia], *Ha = Hm[ia], *ea = ev[ia], *ha = hv[ia];
    double *Eb = Em[ib], *Gb = Gm[ib], *Hb = Hm[ib], *eb = ev[ib], *hb = hv[ib];
    double *Eo = Em[io], *Go = Gm[io], *Ho = Hm[io], *eo = ev[io], *ho = hv[io];
    // L1: Y = I + Ga@Hb ; J = Ea^T@Hb ; N = Ga@Eb^T ; q1 = Ga@hb
    {
      GJ g0{ Ga, Hb, nullptr, Wb, 256, 1, 256, 1, 256, 1 };
      GJ g1{ Ea, Hb, nullptr, Jb, 1, 256, 256, 1, 256, 0 };
      GJ g2{ Ga, Eb, nullptr, Nb, 256, 1, 1, 256, 256, 0 };
      VJ v0{ Ga, hb, nullptr, q1, 256, 1, 1.0 };
      hipLaunchKernelGGL(k_gemm64, dim3(193), dim3(256), 0, stream, g0, g1, g2, 3, v0, vz, vz);
    }
    // L2: Wb = inv(Wb) via 4 panel launches
    hipLaunchKernelGGL(k_pinv, dim3(64), dim3(256), 0, stream, Wb,  X3b, 0);
    hipLaunchKernelGGL(k_pinv, dim3(64), dim3(256), 0, stream, X3b, Wb,  1);
    hipLaunchKernelGGL(k_pinv, dim3(64), dim3(256), 0, stream, Wb,  X3b, 2);
    hipLaunchKernelGGL(k_pinv, dim3(64), dim3(256), 0, stream, X3b, Wb,  3);
    // L3: P = W@Ea ; T1' = W@N ; w12 = -W@q1 ; u1 = W@ea
    {
      GJ g0{ Wb, Ea, nullptr, Pb, 256, 1, 256, 1, 256, 0 };
      GJ g1{ Wb, Nb, nullptr, T1b, 256, 1, 256, 1, 256, 0 };
      VJ v0{ Wb, q1, nullptr, w12, 256, 1, -1.0 };
      VJ v1{ Wb, ea, nullptr, u1, 256, 1, 1.0 };
      hipLaunchKernelGGL(k_gemm64, dim3(130), dim3(256), 0, stream, g0, g1, gz, 2, v0, v1, vz);
    }
    // L4: Eo = Eb@P ; Go = Gb + Eb@T1' ; Ho = Ha + J@P ;
    //     eo = Eb@w12 + eb ; ho = J@u1 + P^T@hb + ha
    {
      GJ g0{ Eb, Pb, nullptr, Eo, 256, 1, 256, 1, 256, 0 };
      GJ g1{ Eb, T1b, Gb, Go, 256, 1, 256, 1, 256, 0 };
      GJ g2{ Jb, Pb, Ha, Ho, 256, 1, 256, 1, 256, 0 };
      VJ v0{ Eb, w12, eb, eo, 256, 1, 1.0 };
      VJ v1{ Jb, u1, ha, ho, 256, 1, 1.0, Pb, hb, 1, 256, 1.0 };
      hipLaunchKernelGGL(k_gemm64, dim3(194), dim3(256), 0, stream, g0, g1, g2, 3, v0, v1, vz);
    }
  };

  // T2 -> T4 -> T8 -> T16 -> T32 -> T64 -> T72 -> T128 -> T200
  comp(0, 0, 1);   // T2
  comp(1, 1, 0);   // T4
  comp(0, 0, 1);   // T8
  comp(1, 1, 2);   // T16
  comp(2, 2, 0);   // T32
  comp(0, 0, 2);   // T64
  comp(2, 1, 0);   // T72  = T64 o T8
  comp(2, 2, 1);   // T128 = T64 o T64
  comp(1, 0, 2);   // T200 = T128 o T72

  // 200th scan step (ph1 reads fp64 V199/v199 directly; fin2 eliminated)
  hipLaunchKernelGGL(k_ph1, dim3(64), dim3(256), 0, stream, A, B, ws);
  hipLaunchKernelGGL(k_ph2, dim3(65), dim3(256), 0, stream, A, B, ws, 1);
  hipLaunchKernelGGL(k_ph3, dim3(64), dim3(256), 0, stream, ws, 1);
  hipLaunchKernelGGL(k_fin, dim3(65), dim3(256), 0, stream, Wp, bphi, ws);
  int rows = in_sizes[0] / XD;
  int nblk = rows / 128;
  hipLaunchKernelGGL(k_batch, dim3(nblk), dim3(256), 0, stream, x0, ws, out);
}